// Round 1
// baseline (496.498 us; speedup 1.0000x reference)
//
#include <hip/hip_runtime.h>
#include <hip/hip_bf16.h>

#define S 2048
#define DM 2048
#define H 16
#define HD 128

using bf16 = __hip_bfloat16;
typedef __attribute__((ext_vector_type(8))) short bf16x8;
typedef __attribute__((ext_vector_type(8))) unsigned short u16x8;
typedef __attribute__((ext_vector_type(4))) float f32x4;

__device__ inline unsigned short f2bu(float f) {
  bf16 b = __float2bfloat16(f);
  union { bf16 b; unsigned short u; } cv; cv.b = b; return cv.u;
}
__device__ inline float bu2f(unsigned short u) {
  union { bf16 b; unsigned short u; } cv; cv.u = u; return __bfloat162float(cv.b);
}

// ---------------- 1. fp32 -> bf16 convert (x) ----------------
__global__ __launch_bounds__(256) void cvt_kernel(const float* __restrict__ x,
                                                  unsigned short* __restrict__ o) {
  int i = (blockIdx.x * 256 + threadIdx.x) * 4;
  float4 v = *(const float4*)(x + i);
  ushort4 r;
  r.x = f2bu(v.x); r.y = f2bu(v.y); r.z = f2bu(v.z); r.w = f2bu(v.w);
  *(ushort4*)(o + i) = r;
}

// ---------------- 2. transpose-convert weights: W (K x N) f32 -> Wt (N x K) bf16 ----------------
__global__ __launch_bounds__(256) void wtrans_kernel(
    const float* __restrict__ s0, const float* __restrict__ s1, const float* __restrict__ s2,
    const float* __restrict__ s3, const float* __restrict__ s4,
    unsigned short* __restrict__ d0, unsigned short* __restrict__ d1, unsigned short* __restrict__ d2,
    unsigned short* __restrict__ d3, unsigned short* __restrict__ d4) {
  __shared__ float tile[64][65];
  int z = blockIdx.z;
  const float* src = z == 0 ? s0 : z == 1 ? s1 : z == 2 ? s2 : z == 3 ? s3 : s4;
  unsigned short* dst = z == 0 ? d0 : z == 1 ? d1 : z == 2 ? d2 : z == 3 ? d3 : d4;
  int tid = threadIdx.x;
  int by = blockIdx.y * 64;  // k block
  int bx = blockIdx.x * 64;  // n block
  int r0 = tid >> 4;         // 0..15
  int c0 = (tid & 15) * 4;
#pragma unroll
  for (int i = 0; i < 4; i++) {
    int row = r0 + i * 16;
    float4 t = *(const float4*)(src + (size_t)(by + row) * DM + bx + c0);
    tile[row][c0 + 0] = t.x; tile[row][c0 + 1] = t.y;
    tile[row][c0 + 2] = t.z; tile[row][c0 + 3] = t.w;
  }
  __syncthreads();
#pragma unroll
  for (int i = 0; i < 4; i++) {
    int nrow = r0 + i * 16;
    ushort4 o;
    o.x = f2bu(tile[c0 + 0][nrow]);
    o.y = f2bu(tile[c0 + 1][nrow]);
    o.z = f2bu(tile[c0 + 2][nrow]);
    o.w = f2bu(tile[c0 + 3][nrow]);
    *(ushort4*)(dst + (size_t)(bx + nrow) * DM + by + c0) = o;
  }
}

// ---------------- 5. bf16 transpose (v -> Vt) ----------------
__global__ __launch_bounds__(256) void vtrans_kernel(const unsigned short* __restrict__ v,
                                                     unsigned short* __restrict__ vt) {
  __shared__ unsigned short tile[64][72];
  int tid = threadIdx.x;
  int by = blockIdx.y * 64, bx = blockIdx.x * 64;
  int r0 = tid >> 3;        // 0..31
  int c0 = (tid & 7) * 8;
#pragma unroll
  for (int i = 0; i < 2; i++) {
    int row = r0 + i * 32;
    u16x8 t = *(const u16x8*)(v + (size_t)(by + row) * DM + bx + c0);
#pragma unroll
    for (int j = 0; j < 8; j++) tile[row][c0 + j] = t[j];
  }
  __syncthreads();
#pragma unroll
  for (int i = 0; i < 2; i++) {
    int nrow = r0 + i * 32;
    u16x8 o;
#pragma unroll
    for (int j = 0; j < 8; j++) o[j] = tile[c0 + j][nrow];
    *(u16x8*)(vt + (size_t)(bx + nrow) * DM + by + c0) = o;
  }
}

// ---------------- 3/8. NT GEMM: C(M,N) = A(M,K) @ Bt(N,K)^T + bias ----------------
// 128x128 tile, BK=64, 4 waves (2x2), each wave 64x64 via 4x4 mfma_16x16x32 tiles.
template <bool OUTBF>
__global__ __launch_bounds__(256) void gemm_nt_kernel(
    const unsigned short* __restrict__ A,
    const unsigned short* __restrict__ B0, const unsigned short* __restrict__ B1,
    const unsigned short* __restrict__ B2, const unsigned short* __restrict__ B3,
    const float* __restrict__ bias0, const float* __restrict__ bias1,
    const float* __restrict__ bias2, const float* __restrict__ bias3,
    void* __restrict__ C0, void* __restrict__ C1, void* __restrict__ C2, void* __restrict__ C3) {
  __shared__ unsigned short sA[128 * 64];
  __shared__ unsigned short sB[128 * 64];
  int z = blockIdx.z;
  const unsigned short* Bp = z == 0 ? B0 : z == 1 ? B1 : z == 2 ? B2 : B3;
  const float* bias = z == 0 ? bias0 : z == 1 ? bias1 : z == 2 ? bias2 : bias3;
  void* C = z == 0 ? C0 : z == 1 ? C1 : z == 2 ? C2 : C3;
  int tid = threadIdx.x;
  int bm = blockIdx.y * 128, bn = blockIdx.x * 128;
  int wid = tid >> 6, lane = tid & 63;
  int wm = wid >> 1, wn = wid & 1;
  int r16 = lane & 15, quad = lane >> 4;
  int srow = tid >> 3;       // 0..31
  int scol = (tid & 7) * 8;  // element col within BK
  f32x4 acc[4][4] = {};
  for (int kt = 0; kt < DM; kt += 64) {
#pragma unroll
    for (int i = 0; i < 4; i++) {
      int row = srow + i * 32;
      uint4 va = *(const uint4*)(A + (size_t)(bm + row) * DM + kt + scol);
      *(uint4*)(sA + row * 64 + scol) = va;
      uint4 vb = *(const uint4*)(Bp + (size_t)(bn + row) * DM + kt + scol);
      *(uint4*)(sB + row * 64 + scol) = vb;
    }
    __syncthreads();
#pragma unroll
    for (int kk = 0; kk < 2; kk++) {
      bf16x8 af[4], bfr[4];
#pragma unroll
      for (int mt = 0; mt < 4; mt++)
        af[mt] = *(const bf16x8*)(sA + (wm * 64 + mt * 16 + r16) * 64 + kk * 32 + quad * 8);
#pragma unroll
      for (int nt = 0; nt < 4; nt++)
        bfr[nt] = *(const bf16x8*)(sB + (wn * 64 + nt * 16 + r16) * 64 + kk * 32 + quad * 8);
#pragma unroll
      for (int mt = 0; mt < 4; mt++)
#pragma unroll
        for (int nt = 0; nt < 4; nt++)
          acc[mt][nt] = __builtin_amdgcn_mfma_f32_16x16x32_bf16(af[mt], bfr[nt], acc[mt][nt], 0, 0, 0);
    }
    __syncthreads();
  }
#pragma unroll
  for (int nt = 0; nt < 4; nt++) {
    int n = bn + wn * 64 + nt * 16 + r16;
    float bv = bias[n];
#pragma unroll
    for (int mt = 0; mt < 4; mt++) {
      int m0 = bm + wm * 64 + mt * 16 + quad * 4;
#pragma unroll
      for (int r = 0; r < 4; r++) {
        float val = acc[mt][nt][r] + bv;
        if (OUTBF)
          ((unsigned short*)C)[(size_t)(m0 + r) * DM + n] = f2bu(val);
        else
          ((float*)C)[(size_t)(m0 + r) * DM + n] = val;
      }
    }
  }
}

// ---------------- 4. RoPE + xPos (in-place on q,k bf16) ----------------
__global__ __launch_bounds__(256) void rope_kernel(unsigned short* __restrict__ q,
                                                   unsigned short* __restrict__ k) {
  int idx = blockIdx.x * 256 + threadIdx.x;  // S*1024 pair slots
  int s = idx >> 10;
  int p = idx & 1023;
  int t = p & 63;
  int col = ((p >> 6) << 7) + (t << 1);
  size_t off = (size_t)s * DM + col;
  // inv_freq = theta^(-2t/128); ang = s * inv_freq
  float ang = (float)s * exp2f((float)(-2 * t) * (13.287712379549449f / 128.0f));
  float sn, cs;
  sincosf(ang, &sn, &cs);
  float sb = ((float)(2 * t) + 51.2f) * (1.0f / 179.2f);   // (2t + 0.4*128)/(1.4*128)
  float power = ((float)s - 1024.0f) * (1.0f / 512.0f);
  float scale = exp2f(power * log2f(sb));
  float inv_scale = 1.0f / scale;
  unsigned int qu = *(unsigned int*)(q + off);
  float a = bu2f(qu & 0xffff), b = bu2f(qu >> 16);
  float qa = (a * cs - b * sn) * scale;
  float qb2 = (b * cs + a * sn) * scale;
  *(unsigned int*)(q + off) = (unsigned int)f2bu(qa) | ((unsigned int)f2bu(qb2) << 16);
  unsigned int ku = *(unsigned int*)(k + off);
  float c2 = bu2f(ku & 0xffff), d2 = bu2f(ku >> 16);
  float ka = (c2 * cs - d2 * sn) * inv_scale;
  float kb2 = (d2 * cs + c2 * sn) * inv_scale;
  *(unsigned int*)(k + off) = (unsigned int)f2bu(ka) | ((unsigned int)f2bu(kb2) << 16);
}

// ---------------- 6. retention: ret = (QK^T (*) decay) V ----------------
// grid: 16 heads x 32 i-blocks (64 rows each), biggest blocks first. 4 waves/block,
// each wave owns 16 q-rows. Q/K/V fragments loaded direct from global (L1/L2-cached),
// P goes through XOR-swizzled per-wave LDS.
__global__ __launch_bounds__(256) void retention_kernel(
    const unsigned short* __restrict__ q, const unsigned short* __restrict__ k,
    const unsigned short* __restrict__ vt, float* __restrict__ ret) {
  __shared__ unsigned char Plds[4 * 16 * 128];  // 4 waves x 16 rows x 128B (64 bf16)
  int bx = blockIdx.x;
  int h = bx >> 5;
  int ib = 31 - (bx & 31);  // launch big i-blocks first for backfill balance
  int I = ib << 6;
  int tid = threadIdx.x, wid = tid >> 6, lane = tid & 63;
  int r16 = lane & 15, quad = lane >> 4;
  double gamma_d = 1.0 - exp2((double)(-5 - h));
  float l2g = (float)(log2(gamma_d));
  bf16x8 aQ[4];
  size_t qrow = (size_t)(I + wid * 16 + r16);
#pragma unroll
  for (int kk = 0; kk < 4; kk++)
    aQ[kk] = *(const bf16x8*)(q + qrow * DM + h * HD + kk * 32 + quad * 8);
  f32x4 acc[8] = {};
  unsigned char* Pw = Plds + wid * 2048;
  for (int J0 = 0; J0 <= I; J0 += 64) {
    f32x4 sf[4] = {};
#pragma unroll
    for (int nt = 0; nt < 4; nt++) {
      size_t krow = (size_t)(J0 + nt * 16 + r16);
#pragma unroll
      for (int kk = 0; kk < 4; kk++) {
        bf16x8 bK = *(const bf16x8*)(k + krow * DM + h * HD + kk * 32 + quad * 8);
        sf[nt] = __builtin_amdgcn_mfma_f32_16x16x32_bf16(aQ[kk], bK, sf[nt], 0, 0, 0);
      }
    }
    __syncthreads();  // previous P reads done before overwrite
#pragma unroll
    for (int nt = 0; nt < 4; nt++) {
      int j = J0 + nt * 16 + r16;
#pragma unroll
      for (int r = 0; r < 4; r++) {
        int i = I + wid * 16 + quad * 4 + r;
        int d = i - j;
        float pv = (d >= 0) ? sf[nt][r] * exp2f((float)d * l2g) : 0.0f;
        int pr = quad * 4 + r;
        int pcb = (nt * 16 + r16) * 2;
        *(unsigned short*)(Pw + pr * 128 + (pcb ^ ((pr & 7) << 4))) = f2bu(pv);
      }
    }
    __syncthreads();
#pragma unroll
    for (int kk2 = 0; kk2 < 2; kk2++) {
      int cb = kk2 * 64 + quad * 16;
      bf16x8 aP = *(const bf16x8*)(Pw + r16 * 128 + (cb ^ ((r16 & 7) << 4)));
#pragma unroll
      for (int nt2 = 0; nt2 < 8; nt2++) {
        bf16x8 bV = *(const bf16x8*)(vt + (size_t)(h * HD + nt2 * 16 + r16) * DM + J0 + kk2 * 32 + quad * 8);
        acc[nt2] = __builtin_amdgcn_mfma_f32_16x16x32_bf16(aP, bV, acc[nt2], 0, 0, 0);
      }
    }
  }
#pragma unroll
  for (int nt2 = 0; nt2 < 8; nt2++) {
    int dcol = h * HD + nt2 * 16 + r16;
#pragma unroll
    for (int r = 0; r < 4; r++) {
      int i = I + wid * 16 + quad * 4 + r;
      ret[(size_t)i * DM + dcol] = acc[nt2][r];
    }
  }
}

// ---------------- 7. GroupNorm (per s,h over 128) + SiLU gate ----------------
__global__ __launch_bounds__(256) void gn_gate_kernel(const float* __restrict__ ret,
                                                      const unsigned short* __restrict__ g,
                                                      unsigned short* __restrict__ y) {
  int tid = threadIdx.x;
  int wave = tid >> 6, lane = tid & 63;
  int gidx = blockIdx.x * 4 + wave;  // 0..S*H-1
  int s = gidx >> 4, h = gidx & 15;
  size_t base = (size_t)s * DM + h * HD + lane * 2;
  float2 v = *(const float2*)(ret + base);
  float sum = v.x + v.y;
  float sq = v.x * v.x + v.y * v.y;
#pragma unroll
  for (int o = 32; o > 0; o >>= 1) {
    sum += __shfl_xor(sum, o, 64);
    sq += __shfl_xor(sq, o, 64);
  }
  float mean = sum * 0.0078125f;
  float var = sq * 0.0078125f - mean * mean;
  float rstd = rsqrtf(var + 1e-5f);
  unsigned int gu = *(const unsigned int*)(g + base);
  float g0 = bu2f(gu & 0xffff), g1 = bu2f(gu >> 16);
  float s0 = g0 / (1.0f + expf(-g0));
  float s1 = g1 / (1.0f + expf(-g1));
  float y0 = s0 * (v.x - mean) * rstd;
  float y1 = s1 * (v.y - mean) * rstd;
  *(unsigned int*)(y + base) = (unsigned int)f2bu(y0) | ((unsigned int)f2bu(y1) << 16);
}

extern "C" void kernel_launch(void* const* d_in, const int* in_sizes, int n_in,
                              void* d_out, int out_size, void* d_ws, size_t ws_size,
                              hipStream_t stream) {
  (void)in_sizes; (void)n_in; (void)out_size; (void)ws_size;
  const float* x  = (const float*)d_in[0];
  const float* Wq = (const float*)d_in[1];
  const float* bq = (const float*)d_in[2];
  const float* Wk = (const float*)d_in[3];
  const float* bk = (const float*)d_in[4];
  const float* Wv = (const float*)d_in[5];
  const float* bv = (const float*)d_in[6];
  const float* Wg = (const float*)d_in[7];
  const float* bg = (const float*)d_in[8];
  const float* Wo = (const float*)d_in[9];
  const float* bo = (const float*)d_in[10];

  char* ws = (char*)d_ws;
  const size_t MB = 1ull << 20;
  unsigned short* xb  = (unsigned short*)(ws + 0 * MB);
  unsigned short* wtq = (unsigned short*)(ws + 8 * MB);
  unsigned short* wtk = (unsigned short*)(ws + 16 * MB);
  unsigned short* wtv = (unsigned short*)(ws + 24 * MB);
  unsigned short* wtg = (unsigned short*)(ws + 32 * MB);
  unsigned short* wto = (unsigned short*)(ws + 40 * MB);
  unsigned short* qb  = (unsigned short*)(ws + 48 * MB);
  unsigned short* kb  = (unsigned short*)(ws + 56 * MB);
  unsigned short* vb  = (unsigned short*)(ws + 64 * MB);
  unsigned short* gb  = (unsigned short*)(ws + 72 * MB);
  unsigned short* vt  = (unsigned short*)(ws + 80 * MB);
  float*          rt  = (float*)(ws + 88 * MB);
  unsigned short* yb  = (unsigned short*)(ws + 104 * MB);

  cvt_kernel<<<4096, 256, 0, stream>>>(x, xb);
  wtrans_kernel<<<dim3(32, 32, 5), 256, 0, stream>>>(Wq, Wk, Wv, Wg, Wo, wtq, wtk, wtv, wtg, wto);
  gemm_nt_kernel<true><<<dim3(16, 16, 4), 256, 0, stream>>>(
      xb, wtq, wtk, wtv, wtg, bq, bk, bv, bg, qb, kb, vb, gb);
  rope_kernel<<<8192, 256, 0, stream>>>(qb, kb);
  vtrans_kernel<<<dim3(32, 32), 256, 0, stream>>>(vb, vt);
  retention_kernel<<<512, 256, 0, stream>>>(qb, kb, vt, rt);
  gn_gate_kernel<<<8192, 256, 0, stream>>>(rt, gb, yb);
  gemm_nt_kernel<false><<<dim3(16, 16, 1), 256, 0, stream>>>(
      yb, wto, wto, wto, wto, bo, bo, bo, bo, d_out, d_out, d_out, d_out);
}

// Round 2
// 218.037 us; speedup vs baseline: 2.2771x; 2.2771x over previous
//
#include <hip/hip_runtime.h>
#include <hip/hip_bf16.h>

#define S 2048
#define DM 2048
#define H 16
#define HD 128

using bf16 = __hip_bfloat16;
typedef __attribute__((ext_vector_type(8))) short bf16x8;
typedef __attribute__((ext_vector_type(8))) unsigned short u16x8;
typedef __attribute__((ext_vector_type(4))) float f32x4;

__device__ __forceinline__ unsigned short f2bu(float f) {
  bf16 b = __float2bfloat16(f);
  union { bf16 b; unsigned short u; } cv; cv.b = b; return cv.u;
}
__device__ __forceinline__ float bu2f(unsigned short u) {
  union { bf16 b; unsigned short u; } cv; cv.u = u; return __bfloat162float(cv.b);
}

// async global -> LDS, 16B per lane. Dest is wave-uniform base + lane*16 (we pass
// per-lane dest that satisfies exactly that). Source is per-lane (pre-swizzled).
__device__ __forceinline__ void async_copy16(const void* g, void* l) {
  __builtin_amdgcn_global_load_lds(
      (const __attribute__((address_space(1))) void*)g,
      (__attribute__((address_space(3))) void*)l, 16, 0, 0);
}

// ---------------- 1. fp32 -> bf16 convert (x) ----------------
__global__ __launch_bounds__(256) void cvt_kernel(const float* __restrict__ x,
                                                  unsigned short* __restrict__ o) {
  int i = (blockIdx.x * 256 + threadIdx.x) * 4;
  float4 v = *(const float4*)(x + i);
  ushort4 r;
  r.x = f2bu(v.x); r.y = f2bu(v.y); r.z = f2bu(v.z); r.w = f2bu(v.w);
  *(ushort4*)(o + i) = r;
}

// ---------------- 2. transpose-convert weights: W (K x N) f32 -> Wt (N x K) bf16 ----------------
__global__ __launch_bounds__(256) void wtrans_kernel(
    const float* __restrict__ s0, const float* __restrict__ s1, const float* __restrict__ s2,
    const float* __restrict__ s3, const float* __restrict__ s4,
    unsigned short* __restrict__ d0, unsigned short* __restrict__ d1, unsigned short* __restrict__ d2,
    unsigned short* __restrict__ d3, unsigned short* __restrict__ d4) {
  __shared__ float tile[64][65];
  int z = blockIdx.z;
  const float* src = z == 0 ? s0 : z == 1 ? s1 : z == 2 ? s2 : z == 3 ? s3 : s4;
  unsigned short* dst = z == 0 ? d0 : z == 1 ? d1 : z == 2 ? d2 : z == 3 ? d3 : d4;
  int tid = threadIdx.x;
  int by = blockIdx.y * 64;  // k block
  int bx = blockIdx.x * 64;  // n block
  int r0 = tid >> 4;
  int c0 = (tid & 15) * 4;
#pragma unroll
  for (int i = 0; i < 4; i++) {
    int row = r0 + i * 16;
    float4 t = *(const float4*)(src + (size_t)(by + row) * DM + bx + c0);
    tile[row][c0 + 0] = t.x; tile[row][c0 + 1] = t.y;
    tile[row][c0 + 2] = t.z; tile[row][c0 + 3] = t.w;
  }
  __syncthreads();
#pragma unroll
  for (int i = 0; i < 4; i++) {
    int nrow = r0 + i * 16;
    ushort4 o;
    o.x = f2bu(tile[c0 + 0][nrow]);
    o.y = f2bu(tile[c0 + 1][nrow]);
    o.z = f2bu(tile[c0 + 2][nrow]);
    o.w = f2bu(tile[c0 + 3][nrow]);
    *(ushort4*)(dst + (size_t)(bx + nrow) * DM + by + c0) = o;
  }
}

// ---------------- 5. bf16 transpose (v -> Vt) ----------------
__global__ __launch_bounds__(256) void vtrans_kernel(const unsigned short* __restrict__ v,
                                                     unsigned short* __restrict__ vt) {
  __shared__ unsigned short tile[64][72];
  int tid = threadIdx.x;
  int by = blockIdx.y * 64, bx = blockIdx.x * 64;
  int r0 = tid >> 3;
  int c0 = (tid & 7) * 8;
#pragma unroll
  for (int i = 0; i < 2; i++) {
    int row = r0 + i * 32;
    u16x8 t = *(const u16x8*)(v + (size_t)(by + row) * DM + bx + c0);
#pragma unroll
    for (int j = 0; j < 8; j++) tile[row][c0 + j] = t[j];
  }
  __syncthreads();
#pragma unroll
  for (int i = 0; i < 2; i++) {
    int nrow = r0 + i * 32;
    u16x8 o;
#pragma unroll
    for (int j = 0; j < 8; j++) o[j] = tile[c0 + j][nrow];
    *(u16x8*)(vt + (size_t)(bx + nrow) * DM + by + c0) = o;
  }
}

// ---------------- 3/8. NT GEMM: C(M,N) = A(M,K) @ Bt(N,K)^T + bias ----------------
// 128x128 tile, BK=64, 4 waves. global_load_lds(16B) staging, XOR-swizzled LDS.
template <bool OUTBF>
__global__ __launch_bounds__(256) void gemm_nt_kernel(
    const unsigned short* __restrict__ A,
    const unsigned short* __restrict__ B0, const unsigned short* __restrict__ B1,
    const unsigned short* __restrict__ B2, const unsigned short* __restrict__ B3,
    const float* __restrict__ bias0, const float* __restrict__ bias1,
    const float* __restrict__ bias2, const float* __restrict__ bias3,
    void* __restrict__ C0, void* __restrict__ C1, void* __restrict__ C2, void* __restrict__ C3) {
  __shared__ alignas(16) unsigned char sA[16384];  // 128 rows x 64 cols bf16 (swizzled)
  __shared__ alignas(16) unsigned char sB[16384];
  int z = blockIdx.z;
  const unsigned short* Bp = z == 0 ? B0 : z == 1 ? B1 : z == 2 ? B2 : B3;
  const float* bias = z == 0 ? bias0 : z == 1 ? bias1 : z == 2 ? bias2 : bias3;
  void* C = z == 0 ? C0 : z == 1 ? C1 : z == 2 ? C2 : C3;
  int tid = threadIdx.x;
  int bm = blockIdx.y * 128, bn = blockIdx.x * 128;
  int wid = tid >> 6, lane = tid & 63;
  int wm = wid >> 1, wn = wid & 1;
  int r16 = lane & 15, quad = lane >> 4;
  f32x4 acc[4][4] = {};
  for (int kt = 0; kt < DM; kt += 64) {
#pragma unroll
    for (int r = 0; r < 4; r++) {
      int a = r * 4096 + tid * 16;
      int row = a >> 7;
      int cb = (a & 127) ^ ((row & 7) << 4);  // inverse-swizzled source, linear dest
      async_copy16((const unsigned char*)(A + (size_t)(bm + row) * DM + kt) + cb, sA + a);
      async_copy16((const unsigned char*)(Bp + (size_t)(bn + row) * DM + kt) + cb, sB + a);
    }
    __syncthreads();
#pragma unroll
    for (int kk = 0; kk < 2; kk++) {
      bf16x8 af[4], bfr[4];
#pragma unroll
      for (int mt = 0; mt < 4; mt++) {
        int row = wm * 64 + mt * 16 + r16;
        af[mt] = *(const bf16x8*)(sA + row * 128 + ((quad * 16 + kk * 64) ^ ((row & 7) << 4)));
      }
#pragma unroll
      for (int nt = 0; nt < 4; nt++) {
        int row = wn * 64 + nt * 16 + r16;
        bfr[nt] = *(const bf16x8*)(sB + row * 128 + ((quad * 16 + kk * 64) ^ ((row & 7) << 4)));
      }
#pragma unroll
      for (int mt = 0; mt < 4; mt++)
#pragma unroll
        for (int nt = 0; nt < 4; nt++)
          acc[mt][nt] = __builtin_amdgcn_mfma_f32_16x16x32_bf16(af[mt], bfr[nt], acc[mt][nt], 0, 0, 0);
    }
    __syncthreads();
  }
#pragma unroll
  for (int nt = 0; nt < 4; nt++) {
    int n = bn + wn * 64 + nt * 16 + r16;
    float bv = bias[n];
#pragma unroll
    for (int mt = 0; mt < 4; mt++) {
      int m0 = bm + wm * 64 + mt * 16 + quad * 4;
#pragma unroll
      for (int r = 0; r < 4; r++) {
        float val = acc[mt][nt][r] + bv;
        if (OUTBF)
          ((unsigned short*)C)[(size_t)(m0 + r) * DM + n] = f2bu(val);
        else
          ((float*)C)[(size_t)(m0 + r) * DM + n] = val;
      }
    }
  }
}

// ---------------- 4. RoPE + xPos + decay pre-fold (in-place on q,k bf16) ----------------
// q[s,h,:] *= xpos_scale * gamma_h^s ; k[s,h,:] *= (1/xpos_scale) * gamma_h^(-s)
// so retention's QK^T directly yields S * gamma^(i-j).
__global__ __launch_bounds__(256) void rope_kernel(unsigned short* __restrict__ q,
                                                   unsigned short* __restrict__ k) {
  int idx = blockIdx.x * 256 + threadIdx.x;  // S*1024 pair slots
  int s = idx >> 10;
  int p = idx & 1023;
  int t = p & 63;
  int head = p >> 6;
  int col = (head << 7) + (t << 1);
  size_t off = (size_t)s * DM + col;
  float ang = (float)s * exp2f((float)(-2 * t) * (13.287712379549449f / 128.0f));
  float sn, cs;
  sincosf(ang, &sn, &cs);
  float sb = ((float)(2 * t) + 51.2f) * (1.0f / 179.2f);
  float power = ((float)s - 1024.0f) * (1.0f / 512.0f);
  float scale = exp2f(power * log2f(sb));
  float l2g = log2f(1.0f - exp2f((float)(-5 - head)));  // log2(gamma_h)
  float qsc = scale * exp2f((float)s * l2g);
  float ksc = (1.0f / scale) * exp2f(-(float)s * l2g);
  unsigned int qu = *(unsigned int*)(q + off);
  float a = bu2f(qu & 0xffff), b = bu2f(qu >> 16);
  float qa = (a * cs - b * sn) * qsc;
  float qb2 = (b * cs + a * sn) * qsc;
  *(unsigned int*)(q + off) = (unsigned int)f2bu(qa) | ((unsigned int)f2bu(qb2) << 16);
  unsigned int ku = *(unsigned int*)(k + off);
  float c2 = bu2f(ku & 0xffff), d2 = bu2f(ku >> 16);
  float ka = (c2 * cs - d2 * sn) * ksc;
  float kb2 = (d2 * cs + c2 * sn) * ksc;
  *(unsigned int*)(k + off) = (unsigned int)f2bu(ka) | ((unsigned int)f2bu(kb2) << 16);
}

// ---------------- 6. retention: ret = (QK^T (causal-masked)) V, decay pre-folded ----------------
// 512 blocks: (h, ib) remapped so blocks bx and bx+256 sum to constant work.
// 4 waves x 16 q-rows. K/V tiles staged in LDS via global_load_lds with
// pre-swizzled source; all fragment reads XOR-swizzled (conflict-free).
__global__ __launch_bounds__(256) void retention_kernel(
    const unsigned short* __restrict__ q, const unsigned short* __restrict__ k,
    const unsigned short* __restrict__ vt, float* __restrict__ ret) {
  __shared__ alignas(16) unsigned char sK[16384];   // 64 rows x 128 cols bf16 (256B stride)
  __shared__ alignas(16) unsigned char sV[16384];   // 128 rows x 64 cols bf16 (128B stride)
  __shared__ alignas(16) unsigned char Plds[8192];  // per-wave 16 x 64 bf16 (128B stride)
  int bx = blockIdx.x;
  int hi = bx >> 8;
  int h = ((bx >> 5) & 7) | (hi << 3);
  int ib = hi ? (bx & 31) : (31 - (bx & 31));
  int I = ib << 6;
  int tid = threadIdx.x, wid = tid >> 6, lane = tid & 63;
  int r16 = lane & 15, quad = lane >> 4;
  bf16x8 aQ[4];
  size_t qrow = (size_t)(I + wid * 16 + r16);
#pragma unroll
  for (int kk = 0; kk < 4; kk++)
    aQ[kk] = *(const bf16x8*)(q + qrow * DM + h * HD + kk * 32 + quad * 8);
  f32x4 acc[8] = {};
  unsigned char* Pw = Plds + wid * 2048;
  for (int J0 = 0; J0 <= I; J0 += 64) {
    // stage K (16KB) and V (16KB): 4 rounds x 256 lanes x 16B each
#pragma unroll
    for (int r = 0; r < 4; r++) {
      int a = r * 4096 + tid * 16;
      int rowk = a >> 8;
      int cbk = (a & 255) ^ ((rowk & 7) << 4);
      async_copy16((const unsigned char*)(k + (size_t)(J0 + rowk) * DM + h * HD) + cbk, sK + a);
      int rowv = a >> 7;
      int cbv = (a & 127) ^ ((rowv & 7) << 4);
      async_copy16((const unsigned char*)(vt + (size_t)(h * HD + rowv) * DM + J0) + cbv, sV + a);
    }
    __syncthreads();
    // QK^T
    f32x4 sf[4] = {};
#pragma unroll
    for (int nt = 0; nt < 4; nt++) {
      int row = nt * 16 + r16;
#pragma unroll
      for (int kk = 0; kk < 4; kk++) {
        bf16x8 bK = *(const bf16x8*)(sK + row * 256 + ((kk * 64 + quad * 16) ^ ((row & 7) << 4)));
        sf[nt] = __builtin_amdgcn_mfma_f32_16x16x32_bf16(aQ[kk], bK, sf[nt], 0, 0, 0);
      }
    }
    // mask (diagonal tile only) + P -> bf16 -> per-wave LDS
    bool diag = (J0 == I);
#pragma unroll
    for (int nt = 0; nt < 4; nt++) {
      int j = nt * 16 + r16;  // j relative to J0
#pragma unroll
      for (int r = 0; r < 4; r++) {
        int ii = wid * 16 + quad * 4 + r;  // i relative to I
        float pv = sf[nt][r];
        if (diag && (ii - j) < 0) pv = 0.0f;
        int pr = quad * 4 + r;
        int pcb = (nt * 16 + r16) * 2;
        *(unsigned short*)(Pw + pr * 128 + (pcb ^ ((pr & 7) << 4))) = f2bu(pv);
      }
    }
    // P @ V
#pragma unroll
    for (int kk2 = 0; kk2 < 2; kk2++) {
      int cb = kk2 * 64 + quad * 16;
      bf16x8 aP = *(const bf16x8*)(Pw + r16 * 128 + (cb ^ ((r16 & 7) << 4)));
#pragma unroll
      for (int nt2 = 0; nt2 < 8; nt2++) {
        int row = nt2 * 16 + r16;
        bf16x8 bV = *(const bf16x8*)(sV + row * 128 + ((kk2 * 64 + quad * 16) ^ ((row & 7) << 4)));
        acc[nt2] = __builtin_amdgcn_mfma_f32_16x16x32_bf16(aP, bV, acc[nt2], 0, 0, 0);
      }
    }
    __syncthreads();
  }
#pragma unroll
  for (int nt2 = 0; nt2 < 8; nt2++) {
    int dcol = h * HD + nt2 * 16 + r16;
#pragma unroll
    for (int r = 0; r < 4; r++) {
      int i = I + wid * 16 + quad * 4 + r;
      ret[(size_t)i * DM + dcol] = acc[nt2][r];
    }
  }
}

// ---------------- 7. GroupNorm (per s,h over 128) + SiLU gate ----------------
__global__ __launch_bounds__(256) void gn_gate_kernel(const float* __restrict__ ret,
                                                      const unsigned short* __restrict__ g,
                                                      unsigned short* __restrict__ y) {
  int tid = threadIdx.x;
  int wave = tid >> 6, lane = tid & 63;
  int gidx = blockIdx.x * 4 + wave;
  int s = gidx >> 4, h = gidx & 15;
  size_t base = (size_t)s * DM + h * HD + lane * 2;
  float2 v = *(const float2*)(ret + base);
  float sum = v.x + v.y;
  float sq = v.x * v.x + v.y * v.y;
#pragma unroll
  for (int o = 32; o > 0; o >>= 1) {
    sum += __shfl_xor(sum, o, 64);
    sq += __shfl_xor(sq, o, 64);
  }
  float mean = sum * 0.0078125f;
  float var = sq * 0.0078125f - mean * mean;
  float rstd = rsqrtf(var + 1e-5f);
  unsigned int gu = *(const unsigned int*)(g + base);
  float g0 = bu2f(gu & 0xffff), g1 = bu2f(gu >> 16);
  float s0 = g0 / (1.0f + expf(-g0));
  float s1 = g1 / (1.0f + expf(-g1));
  float y0 = s0 * (v.x - mean) * rstd;
  float y1 = s1 * (v.y - mean) * rstd;
  *(unsigned int*)(y + base) = (unsigned int)f2bu(y0) | ((unsigned int)f2bu(y1) << 16);
}

extern "C" void kernel_launch(void* const* d_in, const int* in_sizes, int n_in,
                              void* d_out, int out_size, void* d_ws, size_t ws_size,
                              hipStream_t stream) {
  (void)in_sizes; (void)n_in; (void)out_size; (void)ws_size;
  const float* x  = (const float*)d_in[0];
  const float* Wq = (const float*)d_in[1];
  const float* bq = (const float*)d_in[2];
  const float* Wk = (const float*)d_in[3];
  const float* bk = (const float*)d_in[4];
  const float* Wv = (const float*)d_in[5];
  const float* bv = (const float*)d_in[6];
  const float* Wg = (const float*)d_in[7];
  const float* bg = (const float*)d_in[8];
  const float* Wo = (const float*)d_in[9];
  const float* bo = (const float*)d_in[10];

  char* ws = (char*)d_ws;
  const size_t MB = 1ull << 20;
  unsigned short* xb  = (unsigned short*)(ws + 0 * MB);
  unsigned short* wtq = (unsigned short*)(ws + 8 * MB);
  unsigned short* wtk = (unsigned short*)(ws + 16 * MB);
  unsigned short* wtv = (unsigned short*)(ws + 24 * MB);
  unsigned short* wtg = (unsigned short*)(ws + 32 * MB);
  unsigned short* wto = (unsigned short*)(ws + 40 * MB);
  unsigned short* qb  = (unsigned short*)(ws + 48 * MB);
  unsigned short* kb  = (unsigned short*)(ws + 56 * MB);
  unsigned short* vb  = (unsigned short*)(ws + 64 * MB);
  unsigned short* gb  = (unsigned short*)(ws + 72 * MB);
  unsigned short* vt  = (unsigned short*)(ws + 80 * MB);
  float*          rt  = (float*)(ws + 88 * MB);
  unsigned short* yb  = (unsigned short*)(ws + 104 * MB);

  cvt_kernel<<<4096, 256, 0, stream>>>(x, xb);
  wtrans_kernel<<<dim3(32, 32, 5), 256, 0, stream>>>(Wq, Wk, Wv, Wg, Wo, wtq, wtk, wtv, wtg, wto);
  gemm_nt_kernel<true><<<dim3(16, 16, 4), 256, 0, stream>>>(
      xb, wtq, wtk, wtv, wtg, bq, bk, bv, bg, qb, kb, vb, gb);
  rope_kernel<<<8192, 256, 0, stream>>>(qb, kb);
  vtrans_kernel<<<dim3(32, 32), 256, 0, stream>>>(vb, vt);
  retention_kernel<<<512, 256, 0, stream>>>(qb, kb, vt, rt);
  gn_gate_kernel<<<8192, 256, 0, stream>>>(rt, gb, yb);
  gemm_nt_kernel<false><<<dim3(16, 16, 1), 256, 0, stream>>>(
      yb, wto, wto, wto, wto, bo, bo, bo, bo, d_out, d_out, d_out, d_out);
}

// Round 4
// 202.939 us; speedup vs baseline: 2.4465x; 1.0744x over previous
//
#include <hip/hip_runtime.h>
#include <hip/hip_bf16.h>

#define S 2048
#define DM 2048
#define H 16
#define HD 128

using bf16 = __hip_bfloat16;
typedef __attribute__((ext_vector_type(8))) short bf16x8;
typedef __attribute__((ext_vector_type(8))) unsigned short u16x8;
typedef __attribute__((ext_vector_type(4))) float f32x4;

__device__ __forceinline__ unsigned short f2bu(float f) {
  bf16 b = __float2bfloat16(f);
  union { bf16 b; unsigned short u; } cv; cv.b = b; return cv.u;
}
__device__ __forceinline__ float bu2f(unsigned short u) {
  union { bf16 b; unsigned short u; } cv; cv.u = u; return __bfloat162float(cv.b);
}

__device__ __forceinline__ void async_copy16(const void* g, void* l) {
  __builtin_amdgcn_global_load_lds(
      (const __attribute__((address_space(1))) void*)g,
      (__attribute__((address_space(3))) void*)l, 16, 0, 0);
}

// ---------------- 1. fp32 -> bf16 convert (x) ----------------
__global__ __launch_bounds__(256) void cvt_kernel(const float* __restrict__ x,
                                                  unsigned short* __restrict__ o) {
  int i = (blockIdx.x * 256 + threadIdx.x) * 4;
  float4 v = *(const float4*)(x + i);
  ushort4 r;
  r.x = f2bu(v.x); r.y = f2bu(v.y); r.z = f2bu(v.z); r.w = f2bu(v.w);
  *(ushort4*)(o + i) = r;
}

// ---------------- 2. transpose-convert weights: W (K x N) f32 -> Wt (N x K) bf16 ----------------
__global__ __launch_bounds__(256) void wtrans_kernel(
    const float* __restrict__ s0, const float* __restrict__ s1, const float* __restrict__ s2,
    const float* __restrict__ s3, const float* __restrict__ s4,
    unsigned short* __restrict__ d0, unsigned short* __restrict__ d1, unsigned short* __restrict__ d2,
    unsigned short* __restrict__ d3, unsigned short* __restrict__ d4) {
  __shared__ float tile[64][65];
  int z = blockIdx.z;
  const float* src = z == 0 ? s0 : z == 1 ? s1 : z == 2 ? s2 : z == 3 ? s3 : s4;
  unsigned short* dst = z == 0 ? d0 : z == 1 ? d1 : z == 2 ? d2 : z == 3 ? d3 : d4;
  int tid = threadIdx.x;
  int by = blockIdx.y * 64;
  int bx = blockIdx.x * 64;
  int r0 = tid >> 4;
  int c0 = (tid & 15) * 4;
#pragma unroll
  for (int i = 0; i < 4; i++) {
    int row = r0 + i * 16;
    float4 t = *(const float4*)(src + (size_t)(by + row) * DM + bx + c0);
    tile[row][c0 + 0] = t.x; tile[row][c0 + 1] = t.y;
    tile[row][c0 + 2] = t.z; tile[row][c0 + 3] = t.w;
  }
  __syncthreads();
#pragma unroll
  for (int i = 0; i < 4; i++) {
    int nrow = r0 + i * 16;
    ushort4 o;
    o.x = f2bu(tile[c0 + 0][nrow]);
    o.y = f2bu(tile[c0 + 1][nrow]);
    o.z = f2bu(tile[c0 + 2][nrow]);
    o.w = f2bu(tile[c0 + 3][nrow]);
    *(ushort4*)(dst + (size_t)(bx + nrow) * DM + by + c0) = o;
  }
}

// ---------------- 5. bf16 transpose (v -> Vt) ----------------
__global__ __launch_bounds__(256) void vtrans_kernel(const unsigned short* __restrict__ v,
                                                     unsigned short* __restrict__ vt) {
  __shared__ unsigned short tile[64][72];
  int tid = threadIdx.x;
  int by = blockIdx.y * 64, bx = blockIdx.x * 64;
  int r0 = tid >> 3;
  int c0 = (tid & 7) * 8;
#pragma unroll
  for (int i = 0; i < 2; i++) {
    int row = r0 + i * 32;
    u16x8 t = *(const u16x8*)(v + (size_t)(by + row) * DM + bx + c0);
#pragma unroll
    for (int j = 0; j < 8; j++) tile[row][c0 + j] = t[j];
  }
  __syncthreads();
#pragma unroll
  for (int i = 0; i < 2; i++) {
    int nrow = r0 + i * 32;
    u16x8 o;
#pragma unroll
    for (int j = 0; j < 8; j++) o[j] = tile[c0 + j][nrow];
    *(u16x8*)(vt + (size_t)(bx + nrow) * DM + by + c0) = o;
  }
}

// ---------------- 3. fused QKVG GEMM: 256x256 tile, 8-wave, 4-phase/K-tile counted-vmcnt ----------------
// C(M=2048, N=8192) = A(2048,2048) @ Wcat(8192,2048)^T + bias, N-chunks -> q,k,v,g.
// Stage order per tile t (during tile t-1's phases): B0,B1,A0,A1. Phases 0/1 read
// {B(kk0/kk1), A0}; phases 2/3 read A1. Boundary vmcnt(2); mid-tile vmcnt(4).
__device__ __forceinline__ void stage_half(const unsigned short* gbase, char* ldsbase, int tid) {
#pragma unroll
  for (int r = 0; r < 2; r++) {
    int a = r * 8192 + tid * 16;
    int row = a >> 7;
    int cb = (a & 127) ^ ((row & 7) << 4);
    async_copy16((const unsigned char*)(gbase + (size_t)row * DM) + cb, ldsbase + a);
  }
}

__global__ __launch_bounds__(512, 2) void gemm_qkvg_kernel(
    const unsigned short* __restrict__ A, const unsigned short* __restrict__ Bm,
    const float* __restrict__ bias0, const float* __restrict__ bias1,
    const float* __restrict__ bias2, const float* __restrict__ bias3,
    unsigned short* __restrict__ C0, unsigned short* __restrict__ C1,
    unsigned short* __restrict__ C2, unsigned short* __restrict__ C3) {
  __shared__ alignas(16) char smem[131072];  // A: 2x32KB, B: 2x32KB (dbuf x 2 halves x 16KB)
  char* sA = smem;
  char* sB = smem + 65536;
  int tid = threadIdx.x;
  // XCD-aware swizzle: 256 wgs, 8 xcds -> each xcd gets one bm row-panel (32 bn tiles)
  int wg = blockIdx.y * 32 + blockIdx.x;
  int swz = (wg & 7) * 32 + (wg >> 3);
  int bm = (swz >> 5) * 256;
  int bn = (swz & 31) * 256;
  int wid = tid >> 6, lane = tid & 63;
  int wm = wid >> 2, wn = wid & 3;        // 2 x 4 waves; wave tile 128(M) x 64(N)
  int r16 = lane & 15, quad = lane >> 4;
  f32x4 acc[8][4] = {};
  bf16x8 bfrag[2][4];
  const int bhalf = (wn >> 1) << 14;
  const int blr0 = ((wn & 1) << 6) + r16;

  // prologue: stage tile 0 fully into buf 0
  stage_half(Bm + (size_t)bn * DM, sB, tid);
  stage_half(Bm + (size_t)(bn + 128) * DM, sB + 16384, tid);
  stage_half(A + (size_t)bm * DM, sA, tid);
  stage_half(A + (size_t)(bm + 128) * DM, sA + 16384, tid);
  asm volatile("s_waitcnt vmcnt(0)" ::: "memory");
  __builtin_amdgcn_s_barrier();

  for (int t = 0; t < 32; ++t) {
    const int buf = (t & 1) << 15;
    const int nbuf = buf ^ 32768;
    const bool more = t < 31;
    const int kn = (t + 1) * 64;
    char* sAc = sA + buf;
    char* sBc = sB + buf;
    bf16x8 afrag[4];

    // ---- phase 0: read B(kk0)+A0(kk0); stage (t+1).B0
#pragma unroll
    for (int nt = 0; nt < 4; ++nt) {
      int lr = blr0 + nt * 16;
      bfrag[0][nt] = *(const bf16x8*)(sBc + bhalf + lr * 128 + ((quad * 16) ^ ((lr & 7) << 4)));
    }
#pragma unroll
    for (int mt = 0; mt < 4; ++mt) {
      int lr = mt * 32 + wm * 16 + r16;
      afrag[mt] = *(const bf16x8*)(sAc + lr * 128 + ((quad * 16) ^ ((lr & 7) << 4)));
    }
    if (more) stage_half(Bm + (size_t)bn * DM + kn, sB + nbuf, tid);
    __builtin_amdgcn_s_barrier();
    asm volatile("s_waitcnt lgkmcnt(0)" ::: "memory");
    __builtin_amdgcn_s_setprio(1);
#pragma unroll
    for (int mt = 0; mt < 4; ++mt)
#pragma unroll
      for (int nt = 0; nt < 4; ++nt)
        acc[mt][nt] = __builtin_amdgcn_mfma_f32_16x16x32_bf16(afrag[mt], bfrag[0][nt], acc[mt][nt], 0, 0, 0);
    __builtin_amdgcn_s_setprio(0);
    __builtin_amdgcn_s_barrier();

    // ---- phase 1: read B(kk1)+A0(kk1); stage (t+1).B1; close vmcnt(4)
#pragma unroll
    for (int nt = 0; nt < 4; ++nt) {
      int lr = blr0 + nt * 16;
      bfrag[1][nt] = *(const bf16x8*)(sBc + bhalf + lr * 128 + ((64 + quad * 16) ^ ((lr & 7) << 4)));
    }
#pragma unroll
    for (int mt = 0; mt < 4; ++mt) {
      int lr = mt * 32 + wm * 16 + r16;
      afrag[mt] = *(const bf16x8*)(sAc + lr * 128 + ((64 + quad * 16) ^ ((lr & 7) << 4)));
    }
    if (more) stage_half(Bm + (size_t)(bn + 128) * DM + kn, sB + nbuf + 16384, tid);
    __builtin_amdgcn_s_barrier();
    asm volatile("s_waitcnt lgkmcnt(0)" ::: "memory");
    __builtin_amdgcn_s_setprio(1);
#pragma unroll
    for (int mt = 0; mt < 4; ++mt)
#pragma unroll
      for (int nt = 0; nt < 4; ++nt)
        acc[mt][nt] = __builtin_amdgcn_mfma_f32_16x16x32_bf16(afrag[mt], bfrag[1][nt], acc[mt][nt], 0, 0, 0);
    __builtin_amdgcn_s_setprio(0);
    if (more) { asm volatile("s_waitcnt vmcnt(4)" ::: "memory"); }
    else      { asm volatile("s_waitcnt vmcnt(0)" ::: "memory"); }
    __builtin_amdgcn_s_barrier();

    // ---- phase 2: read A1(kk0); stage (t+1).A0; mfma mt 4-7 with held B(kk0)
#pragma unroll
    for (int mt = 0; mt < 4; ++mt) {
      int lr = mt * 32 + wm * 16 + r16;
      afrag[mt] = *(const bf16x8*)(sAc + 16384 + lr * 128 + ((quad * 16) ^ ((lr & 7) << 4)));
    }
    if (more) stage_half(A + (size_t)bm * DM + kn, sA + nbuf, tid);
    __builtin_amdgcn_s_barrier();
    asm volatile("s_waitcnt lgkmcnt(0)" ::: "memory");
    __builtin_amdgcn_s_setprio(1);
#pragma unroll
    for (int mt = 0; mt < 4; ++mt)
#pragma unroll
      for (int nt = 0; nt < 4; ++nt)
        acc[4 + mt][nt] = __builtin_amdgcn_mfma_f32_16x16x32_bf16(afrag[mt], bfrag[0][nt], acc[4 + mt][nt], 0, 0, 0);
    __builtin_amdgcn_s_setprio(0);
    __builtin_amdgcn_s_barrier();

    // ---- phase 3: read A1(kk1); stage (t+1).A1; close vmcnt(2)
#pragma unroll
    for (int mt = 0; mt < 4; ++mt) {
      int lr = mt * 32 + wm * 16 + r16;
      afrag[mt] = *(const bf16x8*)(sAc + 16384 + lr * 128 + ((64 + quad * 16) ^ ((lr & 7) << 4)));
    }
    if (more) stage_half(A + (size_t)(bm + 128) * DM + kn, sA + nbuf + 16384, tid);
    __builtin_amdgcn_s_barrier();
    asm volatile("s_waitcnt lgkmcnt(0)" ::: "memory");
    __builtin_amdgcn_s_setprio(1);
#pragma unroll
    for (int mt = 0; mt < 4; ++mt)
#pragma unroll
      for (int nt = 0; nt < 4; ++nt)
        acc[4 + mt][nt] = __builtin_amdgcn_mfma_f32_16x16x32_bf16(afrag[mt], bfrag[1][nt], acc[4 + mt][nt], 0, 0, 0);
    __builtin_amdgcn_s_setprio(0);
    if (more) { asm volatile("s_waitcnt vmcnt(2)" ::: "memory"); }
    __builtin_amdgcn_s_barrier();
  }

  // epilogue: bn is 256-aligned -> single 2048-wide chunk per block
  int ch = bn >> 11;
  const float* bp = ch == 0 ? bias0 : ch == 1 ? bias1 : ch == 2 ? bias2 : bias3;
  unsigned short* Cp = ch == 0 ? C0 : ch == 1 ? C1 : ch == 2 ? C2 : C3;
  int lcb = bn & 2047;
#pragma unroll
  for (int nt = 0; nt < 4; ++nt) {
    int lc = lcb + wn * 64 + nt * 16 + r16;
    float bv = bp[lc];
#pragma unroll
    for (int mt = 0; mt < 8; ++mt) {
      int m0 = bm + (mt >> 2) * 128 + (mt & 3) * 32 + wm * 16 + quad * 4;
#pragma unroll
      for (int rr = 0; rr < 4; ++rr)
        Cp[(size_t)(m0 + rr) * DM + lc] = f2bu(acc[mt][nt][rr] + bv);
    }
  }
}

// ---------------- 8. output NT GEMM (128x128 tile) ----------------
__global__ __launch_bounds__(256) void gemm_out_kernel(
    const unsigned short* __restrict__ A, const unsigned short* __restrict__ Bp,
    const float* __restrict__ bias, float* __restrict__ C) {
  __shared__ alignas(16) unsigned char sA[16384];
  __shared__ alignas(16) unsigned char sB[16384];
  int tid = threadIdx.x;
  int bm = blockIdx.y * 128, bn = blockIdx.x * 128;
  int wid = tid >> 6, lane = tid & 63;
  int wm = wid >> 1, wn = wid & 1;
  int r16 = lane & 15, quad = lane >> 4;
  f32x4 acc[4][4] = {};
  for (int kt = 0; kt < DM; kt += 64) {
#pragma unroll
    for (int r = 0; r < 4; r++) {
      int a = r * 4096 + tid * 16;
      int row = a >> 7;
      int cb = (a & 127) ^ ((row & 7) << 4);
      async_copy16((const unsigned char*)(A + (size_t)(bm + row) * DM + kt) + cb, sA + a);
      async_copy16((const unsigned char*)(Bp + (size_t)(bn + row) * DM + kt) + cb, sB + a);
    }
    __syncthreads();
#pragma unroll
    for (int kk = 0; kk < 2; kk++) {
      bf16x8 af[4], bfr[4];
#pragma unroll
      for (int mt = 0; mt < 4; mt++) {
        int row = wm * 64 + mt * 16 + r16;
        af[mt] = *(const bf16x8*)(sA + row * 128 + ((quad * 16 + kk * 64) ^ ((row & 7) << 4)));
      }
#pragma unroll
      for (int nt = 0; nt < 4; nt++) {
        int row = wn * 64 + nt * 16 + r16;
        bfr[nt] = *(const bf16x8*)(sB + row * 128 + ((quad * 16 + kk * 64) ^ ((row & 7) << 4)));
      }
#pragma unroll
      for (int mt = 0; mt < 4; mt++)
#pragma unroll
        for (int nt = 0; nt < 4; nt++)
          acc[mt][nt] = __builtin_amdgcn_mfma_f32_16x16x32_bf16(af[mt], bfr[nt], acc[mt][nt], 0, 0, 0);
    }
    __syncthreads();
  }
#pragma unroll
  for (int nt = 0; nt < 4; nt++) {
    int n = bn + wn * 64 + nt * 16 + r16;
    float bv = bias[n];
#pragma unroll
    for (int mt = 0; mt < 4; mt++) {
      int m0 = bm + wm * 64 + mt * 16 + quad * 4;
#pragma unroll
      for (int r = 0; r < 4; r++)
        C[(size_t)(m0 + r) * DM + n] = acc[mt][nt][r] + bv;
    }
  }
}

// ---------------- 4. RoPE + xPos + decay pre-fold (in-place on q,k bf16) ----------------
__global__ __launch_bounds__(256) void rope_kernel(unsigned short* __restrict__ q,
                                                   unsigned short* __restrict__ k) {
  int idx = blockIdx.x * 256 + threadIdx.x;
  int s = idx >> 10;
  int p = idx & 1023;
  int t = p & 63;
  int head = p >> 6;
  int col = (head << 7) + (t << 1);
  size_t off = (size_t)s * DM + col;
  float ang = (float)s * exp2f((float)(-2 * t) * (13.287712379549449f / 128.0f));
  float sn, cs;
  sincosf(ang, &sn, &cs);
  float sb = ((float)(2 * t) + 51.2f) * (1.0f / 179.2f);
  float power = ((float)s - 1024.0f) * (1.0f / 512.0f);
  float scale = exp2f(power * log2f(sb));
  float l2g = log2f(1.0f - exp2f((float)(-5 - head)));
  float qsc = scale * exp2f((float)s * l2g);
  float ksc = (1.0f / scale) * exp2f(-(float)s * l2g);
  unsigned int qu = *(unsigned int*)(q + off);
  float a = bu2f(qu & 0xffff), b = bu2f(qu >> 16);
  float qa = (a * cs - b * sn) * qsc;
  float qb2 = (b * cs + a * sn) * qsc;
  *(unsigned int*)(q + off) = (unsigned int)f2bu(qa) | ((unsigned int)f2bu(qb2) << 16);
  unsigned int ku = *(unsigned int*)(k + off);
  float c2 = bu2f(ku & 0xffff), d2 = bu2f(ku >> 16);
  float ka = (c2 * cs - d2 * sn) * ksc;
  float kb2 = (d2 * cs + c2 * sn) * ksc;
  *(unsigned int*)(k + off) = (unsigned int)f2bu(ka) | ((unsigned int)f2bu(kb2) << 16);
}

// ---------------- 6. retention ----------------
__global__ __launch_bounds__(256) void retention_kernel(
    const unsigned short* __restrict__ q, const unsigned short* __restrict__ k,
    const unsigned short* __restrict__ vt, float* __restrict__ ret) {
  __shared__ alignas(16) unsigned char sK[16384];
  __shared__ alignas(16) unsigned char sV[16384];
  __shared__ alignas(16) unsigned char Plds[8192];
  int bx = blockIdx.x;
  int hi = bx >> 8;
  int h = ((bx >> 5) & 7) | (hi << 3);
  int ib = hi ? (bx & 31) : (31 - (bx & 31));
  int I = ib << 6;
  int tid = threadIdx.x, wid = tid >> 6, lane = tid & 63;
  int r16 = lane & 15, quad = lane >> 4;
  bf16x8 aQ[4];
  size_t qrow = (size_t)(I + wid * 16 + r16);
#pragma unroll
  for (int kk = 0; kk < 4; kk++)
    aQ[kk] = *(const bf16x8*)(q + qrow * DM + h * HD + kk * 32 + quad * 8);
  f32x4 acc[8] = {};
  unsigned char* Pw = Plds + wid * 2048;
  for (int J0 = 0; J0 <= I; J0 += 64) {
#pragma unroll
    for (int r = 0; r < 4; r++) {
      int a = r * 4096 + tid * 16;
      int rowk = a >> 8;
      int cbk = (a & 255) ^ ((rowk & 7) << 4);
      async_copy16((const unsigned char*)(k + (size_t)(J0 + rowk) * DM + h * HD) + cbk, sK + a);
      int rowv = a >> 7;
      int cbv = (a & 127) ^ ((rowv & 7) << 4);
      async_copy16((const unsigned char*)(vt + (size_t)(h * HD + rowv) * DM + J0) + cbv, sV + a);
    }
    __syncthreads();
    f32x4 sf[4] = {};
#pragma unroll
    for (int nt = 0; nt < 4; nt++) {
      int row = nt * 16 + r16;
#pragma unroll
      for (int kk = 0; kk < 4; kk++) {
        bf16x8 bK = *(const bf16x8*)(sK + row * 256 + ((kk * 64 + quad * 16) ^ ((row & 7) << 4)));
        sf[nt] = __builtin_amdgcn_mfma_f32_16x16x32_bf16(aQ[kk], bK, sf[nt], 0, 0, 0);
      }
    }
    bool diag = (J0 == I);
#pragma unroll
    for (int nt = 0; nt < 4; nt++) {
      int j = nt * 16 + r16;
#pragma unroll
      for (int r = 0; r < 4; r++) {
        int ii = wid * 16 + quad * 4 + r;
        float pv = sf[nt][r];
        if (diag && (ii - j) < 0) pv = 0.0f;
        int pr = quad * 4 + r;
        int pcb = (nt * 16 + r16) * 2;
        *(unsigned short*)(Pw + pr * 128 + (pcb ^ ((pr & 7) << 4))) = f2bu(pv);
      }
    }
#pragma unroll
    for (int kk2 = 0; kk2 < 2; kk2++) {
      int cb = kk2 * 64 + quad * 16;
      bf16x8 aP = *(const bf16x8*)(Pw + r16 * 128 + (cb ^ ((r16 & 7) << 4)));
#pragma unroll
      for (int nt2 = 0; nt2 < 8; nt2++) {
        int row = nt2 * 16 + r16;
        bf16x8 bV = *(const bf16x8*)(sV + row * 128 + ((kk2 * 64 + quad * 16) ^ ((row & 7) << 4)));
        acc[nt2] = __builtin_amdgcn_mfma_f32_16x16x32_bf16(aP, bV, acc[nt2], 0, 0, 0);
      }
    }
    __syncthreads();
  }
#pragma unroll
  for (int nt2 = 0; nt2 < 8; nt2++) {
    int dcol = h * HD + nt2 * 16 + r16;
#pragma unroll
    for (int r = 0; r < 4; r++) {
      int i = I + wid * 16 + quad * 4 + r;
      ret[(size_t)i * DM + dcol] = acc[nt2][r];
    }
  }
}

// ---------------- 7. GroupNorm + SiLU gate ----------------
__global__ __launch_bounds__(256) void gn_gate_kernel(const float* __restrict__ ret,
                                                      const unsigned short* __restrict__ g,
                                                      unsigned short* __restrict__ y) {
  int tid = threadIdx.x;
  int wave = tid >> 6, lane = tid & 63;
  int gidx = blockIdx.x * 4 + wave;
  int s = gidx >> 4, h = gidx & 15;
  size_t base = (size_t)s * DM + h * HD + lane * 2;
  float2 v = *(const float2*)(ret + base);
  float sum = v.x + v.y;
  float sq = v.x * v.x + v.y * v.y;
#pragma unroll
  for (int o = 32; o > 0; o >>= 1) {
    sum += __shfl_xor(sum, o, 64);
    sq += __shfl_xor(sq, o, 64);
  }
  float mean = sum * 0.0078125f;
  float var = sq * 0.0078125f - mean * mean;
  float rstd = rsqrtf(var + 1e-5f);
  unsigned int gu = *(const unsigned int*)(g + base);
  float g0 = bu2f(gu & 0xffff), g1 = bu2f(gu >> 16);
  float s0 = g0 / (1.0f + expf(-g0));
  float s1 = g1 / (1.0f + expf(-g1));
  float y0 = s0 * (v.x - mean) * rstd;
  float y1 = s1 * (v.y - mean) * rstd;
  *(unsigned int*)(y + base) = (unsigned int)f2bu(y0) | ((unsigned int)f2bu(y1) << 16);
}

extern "C" void kernel_launch(void* const* d_in, const int* in_sizes, int n_in,
                              void* d_out, int out_size, void* d_ws, size_t ws_size,
                              hipStream_t stream) {
  (void)in_sizes; (void)n_in; (void)out_size; (void)ws_size;
  const float* x  = (const float*)d_in[0];
  const float* Wq = (const float*)d_in[1];
  const float* bq = (const float*)d_in[2];
  const float* Wk = (const float*)d_in[3];
  const float* bk = (const float*)d_in[4];
  const float* Wv = (const float*)d_in[5];
  const float* bv = (const float*)d_in[6];
  const float* Wg = (const float*)d_in[7];
  const float* bg = (const float*)d_in[8];
  const float* Wo = (const float*)d_in[9];
  const float* bo = (const float*)d_in[10];

  char* ws = (char*)d_ws;
  const size_t MB = 1ull << 20;
  unsigned short* xb   = (unsigned short*)(ws + 0 * MB);
  unsigned short* wcat = (unsigned short*)(ws + 8 * MB);   // 8192 x 2048 bf16 = 32MB (q|k|v|g)
  unsigned short* wto  = (unsigned short*)(ws + 40 * MB);
  unsigned short* qb   = (unsigned short*)(ws + 48 * MB);
  unsigned short* kb   = (unsigned short*)(ws + 56 * MB);
  unsigned short* vb   = (unsigned short*)(ws + 64 * MB);
  unsigned short* gb   = (unsigned short*)(ws + 72 * MB);
  unsigned short* vt   = (unsigned short*)(ws + 80 * MB);
  float*          rt   = (float*)(ws + 88 * MB);
  unsigned short* yb   = (unsigned short*)(ws + 104 * MB);

  cvt_kernel<<<4096, 256, 0, stream>>>(x, xb);
  wtrans_kernel<<<dim3(32, 32, 5), 256, 0, stream>>>(
      Wq, Wk, Wv, Wg, Wo,
      wcat, wcat + (size_t)2048 * DM, wcat + (size_t)4096 * DM, wcat + (size_t)6144 * DM, wto);
  gemm_qkvg_kernel<<<dim3(32, 8), 512, 0, stream>>>(
      xb, wcat, bq, bk, bv, bg, qb, kb, vb, gb);
  rope_kernel<<<8192, 256, 0, stream>>>(qb, kb);
  vtrans_kernel<<<dim3(32, 32), 256, 0, stream>>>(vb, vt);
  retention_kernel<<<512, 256, 0, stream>>>(qb, kb, vt, rt);
  gn_gate_kernel<<<8192, 256, 0, stream>>>(rt, gb, yb);
  gemm_out_kernel<<<dim3(16, 16), 256, 0, stream>>>(yb, wto, bo, (float*)d_out);
}

// Round 5
// 191.560 us; speedup vs baseline: 2.5919x; 1.0594x over previous
//
#include <hip/hip_runtime.h>
#include <hip/hip_bf16.h>

#define S 2048
#define DM 2048
#define H 16
#define HD 128

using bf16 = __hip_bfloat16;
typedef __attribute__((ext_vector_type(8))) short bf16x8;
typedef __attribute__((ext_vector_type(8))) unsigned short u16x8;
typedef __attribute__((ext_vector_type(4))) float f32x4;

__device__ __forceinline__ unsigned short f2bu(float f) {
  bf16 b = __float2bfloat16(f);
  union { bf16 b; unsigned short u; } cv; cv.b = b; return cv.u;
}
__device__ __forceinline__ float bu2f(unsigned short u) {
  union { bf16 b; unsigned short u; } cv; cv.u = u; return __bfloat162float(cv.b);
}

__device__ __forceinline__ void async_copy16(const void* g, void* l) {
  __builtin_amdgcn_global_load_lds(
      (const __attribute__((address_space(1))) void*)g,
      (__attribute__((address_space(3))) void*)l, 16, 0, 0);
}

// ---------------- 1. fp32 -> bf16 convert (x) ----------------
__global__ __launch_bounds__(256) void cvt_kernel(const float* __restrict__ x,
                                                  unsigned short* __restrict__ o) {
  int i = (blockIdx.x * 256 + threadIdx.x) * 4;
  float4 v = *(const float4*)(x + i);
  ushort4 r;
  r.x = f2bu(v.x); r.y = f2bu(v.y); r.z = f2bu(v.z); r.w = f2bu(v.w);
  *(ushort4*)(o + i) = r;
}

// ---------------- 2. transpose-convert weights: W (K x N) f32 -> Wt (N x K) bf16 ----------------
__global__ __launch_bounds__(256) void wtrans_kernel(
    const float* __restrict__ s0, const float* __restrict__ s1, const float* __restrict__ s2,
    const float* __restrict__ s3, const float* __restrict__ s4,
    unsigned short* __restrict__ d0, unsigned short* __restrict__ d1, unsigned short* __restrict__ d2,
    unsigned short* __restrict__ d3, unsigned short* __restrict__ d4) {
  __shared__ float tile[64][65];
  int z = blockIdx.z;
  const float* src = z == 0 ? s0 : z == 1 ? s1 : z == 2 ? s2 : z == 3 ? s3 : s4;
  unsigned short* dst = z == 0 ? d0 : z == 1 ? d1 : z == 2 ? d2 : z == 3 ? d3 : d4;
  int tid = threadIdx.x;
  int by = blockIdx.y * 64;
  int bx = blockIdx.x * 64;
  int r0 = tid >> 4;
  int c0 = (tid & 15) * 4;
#pragma unroll
  for (int i = 0; i < 4; i++) {
    int row = r0 + i * 16;
    float4 t = *(const float4*)(src + (size_t)(by + row) * DM + bx + c0);
    tile[row][c0 + 0] = t.x; tile[row][c0 + 1] = t.y;
    tile[row][c0 + 2] = t.z; tile[row][c0 + 3] = t.w;
  }
  __syncthreads();
#pragma unroll
  for (int i = 0; i < 4; i++) {
    int nrow = r0 + i * 16;
    ushort4 o;
    o.x = f2bu(tile[c0 + 0][nrow]);
    o.y = f2bu(tile[c0 + 1][nrow]);
    o.z = f2bu(tile[c0 + 2][nrow]);
    o.w = f2bu(tile[c0 + 3][nrow]);
    *(ushort4*)(dst + (size_t)(bx + nrow) * DM + by + c0) = o;
  }
}

// ---------------- 5. bf16 transpose (v -> Vt) ----------------
__global__ __launch_bounds__(256) void vtrans_kernel(const unsigned short* __restrict__ v,
                                                     unsigned short* __restrict__ vt) {
  __shared__ unsigned short tile[64][72];
  int tid = threadIdx.x;
  int by = blockIdx.y * 64, bx = blockIdx.x * 64;
  int r0 = tid >> 3;
  int c0 = (tid & 7) * 8;
#pragma unroll
  for (int i = 0; i < 2; i++) {
    int row = r0 + i * 32;
    u16x8 t = *(const u16x8*)(v + (size_t)(by + row) * DM + bx + c0);
#pragma unroll
    for (int j = 0; j < 8; j++) tile[row][c0 + j] = t[j];
  }
  __syncthreads();
#pragma unroll
  for (int i = 0; i < 2; i++) {
    int nrow = r0 + i * 32;
    u16x8 o;
#pragma unroll
    for (int j = 0; j < 8; j++) o[j] = tile[c0 + j][nrow];
    *(u16x8*)(vt + (size_t)(bx + nrow) * DM + by + c0) = o;
  }
}

// ---------------- 3. fused QKVG GEMM: 256x256 tile, 8-wave, 4-phase/K-tile counted-vmcnt ----------------
// Stage schedule (tile t+1 during tile t): phase0 {B0,B1,A0}, phase2 {A1}.
// Waits: end-ph1 vmcnt(6) [drains A1(t)]; end-ph3 vmcnt(2) [drains trio(t+1)].
// Every load has a 3-phase issue->wait gap. XCD mapping: each XCD owns 4 bn-panels
// (4MB of B, L2-resident) x 8 bm rows; A (8MB) shared via L3.
__device__ __forceinline__ void stage_half(const unsigned short* gbase, char* ldsbase, int tid) {
#pragma unroll
  for (int r = 0; r < 2; r++) {
    int a = r * 8192 + tid * 16;
    int row = a >> 7;
    int cb = (a & 127) ^ ((row & 7) << 4);
    async_copy16((const unsigned char*)(gbase + (size_t)row * DM) + cb, ldsbase + a);
  }
}

__global__ __launch_bounds__(512, 2) void gemm_qkvg_kernel(
    const unsigned short* __restrict__ A, const unsigned short* __restrict__ Bm,
    const float* __restrict__ bias0, const float* __restrict__ bias1,
    const float* __restrict__ bias2, const float* __restrict__ bias3,
    unsigned short* __restrict__ C0, unsigned short* __restrict__ C1,
    unsigned short* __restrict__ C2, unsigned short* __restrict__ C3) {
  __shared__ alignas(16) char smem[131072];
  char* sA = smem;
  char* sB = smem + 65536;
  int tid = threadIdx.x;
  int wg = blockIdx.y * 32 + blockIdx.x;
  int xcd = wg & 7, rr0 = wg >> 3;
  int bm = (rr0 >> 2) * 256;
  int bn = (xcd * 4 + (rr0 & 3)) * 256;
  int wid = tid >> 6, lane = tid & 63;
  int wm = wid >> 2, wn = wid & 3;
  int r16 = lane & 15, quad = lane >> 4;
  f32x4 acc[8][4] = {};
  bf16x8 bfrag[2][4];
  const int bhalf = (wn >> 1) << 14;
  const int blr0 = ((wn & 1) << 6) + r16;

  // prologue: stage tile 0 fully into buf 0
  stage_half(Bm + (size_t)bn * DM, sB, tid);
  stage_half(Bm + (size_t)(bn + 128) * DM, sB + 16384, tid);
  stage_half(A + (size_t)bm * DM, sA, tid);
  stage_half(A + (size_t)(bm + 128) * DM, sA + 16384, tid);
  asm volatile("s_waitcnt vmcnt(0)" ::: "memory");
  __builtin_amdgcn_s_barrier();

  for (int t = 0; t < 32; ++t) {
    const int buf = (t & 1) << 15;
    const int nbuf = buf ^ 32768;
    const bool more = t < 31;
    const int kn = (t + 1) * 64;
    char* sAc = sA + buf;
    char* sBc = sB + buf;
    bf16x8 afrag[4];

    // ---- phase 0: read B(kk0)+A0(kk0); stage (t+1): B0, B1, A0
#pragma unroll
    for (int nt = 0; nt < 4; ++nt) {
      int lr = blr0 + nt * 16;
      bfrag[0][nt] = *(const bf16x8*)(sBc + bhalf + lr * 128 + ((quad * 16) ^ ((lr & 7) << 4)));
    }
#pragma unroll
    for (int mt = 0; mt < 4; ++mt) {
      int lr = mt * 32 + wm * 16 + r16;
      afrag[mt] = *(const bf16x8*)(sAc + lr * 128 + ((quad * 16) ^ ((lr & 7) << 4)));
    }
    if (more) {
      stage_half(Bm + (size_t)bn * DM + kn, sB + nbuf, tid);
      stage_half(Bm + (size_t)(bn + 128) * DM + kn, sB + nbuf + 16384, tid);
      stage_half(A + (size_t)bm * DM + kn, sA + nbuf, tid);
    }
    __builtin_amdgcn_s_barrier();
    asm volatile("s_waitcnt lgkmcnt(0)" ::: "memory");
    __builtin_amdgcn_s_setprio(1);
#pragma unroll
    for (int mt = 0; mt < 4; ++mt)
#pragma unroll
      for (int nt = 0; nt < 4; ++nt)
        acc[mt][nt] = __builtin_amdgcn_mfma_f32_16x16x32_bf16(afrag[mt], bfrag[0][nt], acc[mt][nt], 0, 0, 0);
    __builtin_amdgcn_s_setprio(0);
    __builtin_amdgcn_s_barrier();

    // ---- phase 1: read B(kk1)+A0(kk1); close vmcnt(6) [drain A1(t)]
#pragma unroll
    for (int nt = 0; nt < 4; ++nt) {
      int lr = blr0 + nt * 16;
      bfrag[1][nt] = *(const bf16x8*)(sBc + bhalf + lr * 128 + ((64 + quad * 16) ^ ((lr & 7) << 4)));
    }
#pragma unroll
    for (int mt = 0; mt < 4; ++mt) {
      int lr = mt * 32 + wm * 16 + r16;
      afrag[mt] = *(const bf16x8*)(sAc + lr * 128 + ((64 + quad * 16) ^ ((lr & 7) << 4)));
    }
    __builtin_amdgcn_s_barrier();
    asm volatile("s_waitcnt lgkmcnt(0)" ::: "memory");
    __builtin_amdgcn_s_setprio(1);
#pragma unroll
    for (int mt = 0; mt < 4; ++mt)
#pragma unroll
      for (int nt = 0; nt < 4; ++nt)
        acc[mt][nt] = __builtin_amdgcn_mfma_f32_16x16x32_bf16(afrag[mt], bfrag[1][nt], acc[mt][nt], 0, 0, 0);
    __builtin_amdgcn_s_setprio(0);
    if (more) { asm volatile("s_waitcnt vmcnt(6)" ::: "memory"); }
    else      { asm volatile("s_waitcnt vmcnt(0)" ::: "memory"); }
    __builtin_amdgcn_s_barrier();

    // ---- phase 2: read A1(kk0); stage (t+1).A1; mfma acc[4..7] with held B(kk0)
#pragma unroll
    for (int mt = 0; mt < 4; ++mt) {
      int lr = mt * 32 + wm * 16 + r16;
      afrag[mt] = *(const bf16x8*)(sAc + 16384 + lr * 128 + ((quad * 16) ^ ((lr & 7) << 4)));
    }
    if (more) stage_half(A + (size_t)(bm + 128) * DM + kn, sA + nbuf + 16384, tid);
    __builtin_amdgcn_s_barrier();
    asm volatile("s_waitcnt lgkmcnt(0)" ::: "memory");
    __builtin_amdgcn_s_setprio(1);
#pragma unroll
    for (int mt = 0; mt < 4; ++mt)
#pragma unroll
      for (int nt = 0; nt < 4; ++nt)
        acc[4 + mt][nt] = __builtin_amdgcn_mfma_f32_16x16x32_bf16(afrag[mt], bfrag[0][nt], acc[4 + mt][nt], 0, 0, 0);
    __builtin_amdgcn_s_setprio(0);
    __builtin_amdgcn_s_barrier();

    // ---- phase 3: read A1(kk1); close vmcnt(2) [drain trio(t+1)]
#pragma unroll
    for (int mt = 0; mt < 4; ++mt) {
      int lr = mt * 32 + wm * 16 + r16;
      afrag[mt] = *(const bf16x8*)(sAc + 16384 + lr * 128 + ((64 + quad * 16) ^ ((lr & 7) << 4)));
    }
    __builtin_amdgcn_s_barrier();
    asm volatile("s_waitcnt lgkmcnt(0)" ::: "memory");
    __builtin_amdgcn_s_setprio(1);
#pragma unroll
    for (int mt = 0; mt < 4; ++mt)
#pragma unroll
      for (int nt = 0; nt < 4; ++nt)
        acc[4 + mt][nt] = __builtin_amdgcn_mfma_f32_16x16x32_bf16(afrag[mt], bfrag[1][nt], acc[4 + mt][nt], 0, 0, 0);
    __builtin_amdgcn_s_setprio(0);
    if (more) { asm volatile("s_waitcnt vmcnt(2)" ::: "memory"); }
    __builtin_amdgcn_s_barrier();
  }

  // epilogue
  int ch = bn >> 11;
  const float* bp = ch == 0 ? bias0 : ch == 1 ? bias1 : ch == 2 ? bias2 : bias3;
  unsigned short* Cp = ch == 0 ? C0 : ch == 1 ? C1 : ch == 2 ? C2 : C3;
  int lcb = bn & 2047;
#pragma unroll
  for (int nt = 0; nt < 4; ++nt) {
    int lc = lcb + wn * 64 + nt * 16 + r16;
    float bv = bp[lc];
#pragma unroll
    for (int mt = 0; mt < 8; ++mt) {
      int m0 = bm + (mt >> 2) * 128 + (mt & 3) * 32 + wm * 16 + quad * 4;
#pragma unroll
      for (int rrr = 0; rrr < 4; ++rrr)
        Cp[(size_t)(m0 + rrr) * DM + lc] = f2bu(acc[mt][nt][rrr] + bv);
    }
  }
}

// ---------------- 8. output NT GEMM (128x128 tile) ----------------
__global__ __launch_bounds__(256) void gemm_out_kernel(
    const unsigned short* __restrict__ A, const unsigned short* __restrict__ Bp,
    const float* __restrict__ bias, float* __restrict__ C) {
  __shared__ alignas(16) unsigned char sA[16384];
  __shared__ alignas(16) unsigned char sB[16384];
  int tid = threadIdx.x;
  int bm = blockIdx.y * 128, bn = blockIdx.x * 128;
  int wid = tid >> 6, lane = tid & 63;
  int wm = wid >> 1, wn = wid & 1;
  int r16 = lane & 15, quad = lane >> 4;
  f32x4 acc[4][4] = {};
  for (int kt = 0; kt < DM; kt += 64) {
#pragma unroll
    for (int r = 0; r < 4; r++) {
      int a = r * 4096 + tid * 16;
      int row = a >> 7;
      int cb = (a & 127) ^ ((row & 7) << 4);
      async_copy16((const unsigned char*)(A + (size_t)(bm + row) * DM + kt) + cb, sA + a);
      async_copy16((const unsigned char*)(Bp + (size_t)(bn + row) * DM + kt) + cb, sB + a);
    }
    __syncthreads();
#pragma unroll
    for (int kk = 0; kk < 2; kk++) {
      bf16x8 af[4], bfr[4];
#pragma unroll
      for (int mt = 0; mt < 4; mt++) {
        int row = wm * 64 + mt * 16 + r16;
        af[mt] = *(const bf16x8*)(sA + row * 128 + ((quad * 16 + kk * 64) ^ ((row & 7) << 4)));
      }
#pragma unroll
      for (int nt = 0; nt < 4; nt++) {
        int row = wn * 64 + nt * 16 + r16;
        bfr[nt] = *(const bf16x8*)(sB + row * 128 + ((quad * 16 + kk * 64) ^ ((row & 7) << 4)));
      }
#pragma unroll
      for (int mt = 0; mt < 4; mt++)
#pragma unroll
        for (int nt = 0; nt < 4; nt++)
          acc[mt][nt] = __builtin_amdgcn_mfma_f32_16x16x32_bf16(af[mt], bfr[nt], acc[mt][nt], 0, 0, 0);
    }
    __syncthreads();
  }
#pragma unroll
  for (int nt = 0; nt < 4; nt++) {
    int n = bn + wn * 64 + nt * 16 + r16;
    float bv = bias[n];
#pragma unroll
    for (int mt = 0; mt < 4; mt++) {
      int m0 = bm + wm * 64 + mt * 16 + quad * 4;
#pragma unroll
      for (int r = 0; r < 4; r++)
        C[(size_t)(m0 + r) * DM + n] = acc[mt][nt][r] + bv;
    }
  }
}

// ---------------- 4. RoPE + xPos + decay pre-fold (in-place on q,k bf16) ----------------
__global__ __launch_bounds__(256) void rope_kernel(unsigned short* __restrict__ q,
                                                   unsigned short* __restrict__ k) {
  int idx = blockIdx.x * 256 + threadIdx.x;
  int s = idx >> 10;
  int p = idx & 1023;
  int t = p & 63;
  int head = p >> 6;
  int col = (head << 7) + (t << 1);
  size_t off = (size_t)s * DM + col;
  float ang = (float)s * exp2f((float)(-2 * t) * (13.287712379549449f / 128.0f));
  float sn, cs;
  sincosf(ang, &sn, &cs);
  float sb = ((float)(2 * t) + 51.2f) * (1.0f / 179.2f);
  float power = ((float)s - 1024.0f) * (1.0f / 512.0f);
  float scale = exp2f(power * log2f(sb));
  float l2g = log2f(1.0f - exp2f((float)(-5 - head)));
  float qsc = scale * exp2f((float)s * l2g);
  float ksc = (1.0f / scale) * exp2f(-(float)s * l2g);
  unsigned int qu = *(unsigned int*)(q + off);
  float a = bu2f(qu & 0xffff), b = bu2f(qu >> 16);
  float qa = (a * cs - b * sn) * qsc;
  float qb2 = (b * cs + a * sn) * qsc;
  *(unsigned int*)(q + off) = (unsigned int)f2bu(qa) | ((unsigned int)f2bu(qb2) << 16);
  unsigned int ku = *(unsigned int*)(k + off);
  float c2 = bu2f(ku & 0xffff), d2 = bu2f(ku >> 16);
  float ka = (c2 * cs - d2 * sn) * ksc;
  float kb2 = (d2 * cs + c2 * sn) * ksc;
  *(unsigned int*)(k + off) = (unsigned int)f2bu(ka) | ((unsigned int)f2bu(kb2) << 16);
}

// ---------------- 6. retention: double-buffered K/V staging, counted vmcnt ----------------
__device__ __forceinline__ void stage_kv(const unsigned short* __restrict__ k,
                                         const unsigned short* __restrict__ vt,
                                         int h, int J0, unsigned char* dK,
                                         unsigned char* dV, int tid) {
#pragma unroll
  for (int r = 0; r < 4; r++) {
    int a = r * 4096 + tid * 16;
    int rowk = a >> 8;
    int cbk = (a & 255) ^ ((rowk & 7) << 4);
    async_copy16((const unsigned char*)(k + (size_t)(J0 + rowk) * DM + h * HD) + cbk, dK + a);
    int rowv = a >> 7;
    int cbv = (a & 127) ^ ((rowv & 7) << 4);
    async_copy16((const unsigned char*)(vt + (size_t)(h * HD + rowv) * DM + J0) + cbv, dV + a);
  }
}

__global__ __launch_bounds__(256) void retention_kernel(
    const unsigned short* __restrict__ q, const unsigned short* __restrict__ k,
    const unsigned short* __restrict__ vt, float* __restrict__ ret) {
  __shared__ alignas(16) unsigned char sK[2][16384];
  __shared__ alignas(16) unsigned char sV[2][16384];
  __shared__ alignas(16) unsigned char Plds[8192];
  int bx = blockIdx.x;
  int hi = bx >> 8;
  int h = ((bx >> 5) & 7) | (hi << 3);
  int ib = hi ? (bx & 31) : (31 - (bx & 31));
  int I = ib << 6;
  int tid = threadIdx.x, wid = tid >> 6, lane = tid & 63;
  int r16 = lane & 15, quad = lane >> 4;
  bf16x8 aQ[4];
  size_t qrow = (size_t)(I + wid * 16 + r16);
#pragma unroll
  for (int kk = 0; kk < 4; kk++)
    aQ[kk] = *(const bf16x8*)(q + qrow * DM + h * HD + kk * 32 + quad * 8);
  f32x4 acc[8] = {};
  unsigned char* Pw = Plds + wid * 2048;
  stage_kv(k, vt, h, 0, sK[0], sV[0], tid);  // prologue: 8 loads into buf0
  for (int J0 = 0; J0 <= I; J0 += 64) {
    int cur = (J0 >> 6) & 1;
    bool more = (J0 + 64) <= I;
    if (more) stage_kv(k, vt, h, J0 + 64, sK[cur ^ 1], sV[cur ^ 1], tid);
    if (more) { asm volatile("s_waitcnt vmcnt(8)" ::: "memory"); }
    else      { asm volatile("s_waitcnt vmcnt(0)" ::: "memory"); }
    __builtin_amdgcn_s_barrier();
    const unsigned char* sKc = sK[cur];
    const unsigned char* sVc = sV[cur];
    // QK^T
    f32x4 sf[4] = {};
#pragma unroll
    for (int nt = 0; nt < 4; nt++) {
      int row = nt * 16 + r16;
#pragma unroll
      for (int kk = 0; kk < 4; kk++) {
        bf16x8 bK = *(const bf16x8*)(sKc + row * 256 + ((kk * 64 + quad * 16) ^ ((row & 7) << 4)));
        sf[nt] = __builtin_amdgcn_mfma_f32_16x16x32_bf16(aQ[kk], bK, sf[nt], 0, 0, 0);
      }
    }
    // mask (diagonal tile only) + P -> bf16 -> per-wave LDS (no barrier needed)
    bool diag = (J0 == I);
#pragma unroll
    for (int nt = 0; nt < 4; nt++) {
      int j = nt * 16 + r16;
#pragma unroll
      for (int r = 0; r < 4; r++) {
        int ii = wid * 16 + quad * 4 + r;
        float pv = sf[nt][r];
        if (diag && (ii - j) < 0) pv = 0.0f;
        int pr = quad * 4 + r;
        int pcb = (nt * 16 + r16) * 2;
        *(unsigned short*)(Pw + pr * 128 + (pcb ^ ((pr & 7) << 4))) = f2bu(pv);
      }
    }
    // P @ V
#pragma unroll
    for (int kk2 = 0; kk2 < 2; kk2++) {
      int cb = kk2 * 64 + quad * 16;
      bf16x8 aP = *(const bf16x8*)(Pw + r16 * 128 + (cb ^ ((r16 & 7) << 4)));
#pragma unroll
      for (int nt2 = 0; nt2 < 8; nt2++) {
        int row = nt2 * 16 + r16;
        bf16x8 bV = *(const bf16x8*)(sVc + row * 128 + ((kk2 * 64 + quad * 16) ^ ((row & 7) << 4)));
        acc[nt2] = __builtin_amdgcn_mfma_f32_16x16x32_bf16(aP, bV, acc[nt2], 0, 0, 0);
      }
    }
    __builtin_amdgcn_s_barrier();  // all waves done with buf[cur] before overwrite
  }
#pragma unroll
  for (int nt2 = 0; nt2 < 8; nt2++) {
    int dcol = h * HD + nt2 * 16 + r16;
#pragma unroll
    for (int r = 0; r < 4; r++) {
      int i = I + wid * 16 + quad * 4 + r;
      ret[(size_t)i * DM + dcol] = acc[nt2][r];
    }
  }
}

// ---------------- 7. GroupNorm + SiLU gate ----------------
__global__ __launch_bounds__(256) void gn_gate_kernel(const float* __restrict__ ret,
                                                      const unsigned short* __restrict__ g,
                                                      unsigned short* __restrict__ y) {
  int tid = threadIdx.x;
  int wave = tid >> 6, lane = tid & 63;
  int gidx = blockIdx.x * 4 + wave;
  int s = gidx >> 4, h = gidx & 15;
  size_t base = (size_t)s * DM + h * HD + lane * 2;
  float2 v = *(const float2*)(ret + base);
  float sum = v.x + v.y;
  float sq = v.x * v.x + v.y * v.y;
#pragma unroll
  for (int o = 32; o > 0; o >>= 1) {
    sum += __shfl_xor(sum, o, 64);
    sq += __shfl_xor(sq, o, 64);
  }
  float mean = sum * 0.0078125f;
  float var = sq * 0.0078125f - mean * mean;
  float rstd = rsqrtf(var + 1e-5f);
  unsigned int gu = *(const unsigned int*)(g + base);
  float g0 = bu2f(gu & 0xffff), g1 = bu2f(gu >> 16);
  float s0 = g0 / (1.0f + expf(-g0));
  float s1 = g1 / (1.0f + expf(-g1));
  float y0 = s0 * (v.x - mean) * rstd;
  float y1 = s1 * (v.y - mean) * rstd;
  *(unsigned int*)(y + base) = (unsigned int)f2bu(y0) | ((unsigned int)f2bu(y1) << 16);
}

extern "C" void kernel_launch(void* const* d_in, const int* in_sizes, int n_in,
                              void* d_out, int out_size, void* d_ws, size_t ws_size,
                              hipStream_t stream) {
  (void)in_sizes; (void)n_in; (void)out_size; (void)ws_size;
  const float* x  = (const float*)d_in[0];
  const float* Wq = (const float*)d_in[1];
  const float* bq = (const float*)d_in[2];
  const float* Wk = (const float*)d_in[3];
  const float* bk = (const float*)d_in[4];
  const float* Wv = (const float*)d_in[5];
  const float* bv = (const float*)d_in[6];
  const float* Wg = (const float*)d_in[7];
  const float* bg = (const float*)d_in[8];
  const float* Wo = (const float*)d_in[9];
  const float* bo = (const float*)d_in[10];

  char* ws = (char*)d_ws;
  const size_t MB = 1ull << 20;
  unsigned short* xb   = (unsigned short*)(ws + 0 * MB);
  unsigned short* wcat = (unsigned short*)(ws + 8 * MB);   // 8192 x 2048 bf16 (q|k|v|g)
  unsigned short* wto  = (unsigned short*)(ws + 40 * MB);
  unsigned short* qb   = (unsigned short*)(ws + 48 * MB);
  unsigned short* kb   = (unsigned short*)(ws + 56 * MB);
  unsigned short* vb   = (unsigned short*)(ws + 64 * MB);
  unsigned short* gb   = (unsigned short*)(ws + 72 * MB);
  unsigned short* vt   = (unsigned short*)(ws + 80 * MB);
  float*          rt   = (float*)(ws + 88 * MB);
  unsigned short* yb   = (unsigned short*)(ws + 104 * MB);

  cvt_kernel<<<4096, 256, 0, stream>>>(x, xb);
  wtrans_kernel<<<dim3(32, 32, 5), 256, 0, stream>>>(
      Wq, Wk, Wv, Wg, Wo,
      wcat, wcat + (size_t)2048 * DM, wcat + (size_t)4096 * DM, wcat + (size_t)6144 * DM, wto);
  gemm_qkvg_kernel<<<dim3(32, 8), 512, 0, stream>>>(
      xb, wcat, bq, bk, bv, bg, qb, kb, vb, gb);
  rope_kernel<<<8192, 256, 0, stream>>>(qb, kb);
  vtrans_kernel<<<dim3(32, 32), 256, 0, stream>>>(vb, vt);
  retention_kernel<<<512, 256, 0, stream>>>(qb, kb, vt, rt);
  gn_gate_kernel<<<8192, 256, 0, stream>>>(rt, gb, yb);
  gemm_out_kernel<<<dim3(16, 16), 256, 0, stream>>>(yb, wto, bo, (float*)d_out);
}

// Round 6
// 182.334 us; speedup vs baseline: 2.7230x; 1.0506x over previous
//
#include <hip/hip_runtime.h>
#include <hip/hip_bf16.h>

#define S 2048
#define DM 2048
#define H 16
#define HD 128

using bf16 = __hip_bfloat16;
typedef __attribute__((ext_vector_type(8))) short bf16x8;
typedef __attribute__((ext_vector_type(8))) unsigned short u16x8;
typedef __attribute__((ext_vector_type(4))) float f32x4;

__device__ __forceinline__ unsigned short f2bu(float f) {
  bf16 b = __float2bfloat16(f);
  union { bf16 b; unsigned short u; } cv; cv.b = b; return cv.u;
}
__device__ __forceinline__ float bu2f(unsigned short u) {
  union { bf16 b; unsigned short u; } cv; cv.u = u; return __bfloat162float(cv.b);
}

__device__ __forceinline__ void async_copy16(const void* g, void* l) {
  __builtin_amdgcn_global_load_lds(
      (const __attribute__((address_space(1))) void*)g,
      (__attribute__((address_space(3))) void*)l, 16, 0, 0);
}

// ---------------- 1. fp32 -> bf16 convert (x) ----------------
__global__ __launch_bounds__(256) void cvt_kernel(const float* __restrict__ x,
                                                  unsigned short* __restrict__ o) {
  int i = (blockIdx.x * 256 + threadIdx.x) * 4;
  float4 v = *(const float4*)(x + i);
  ushort4 r;
  r.x = f2bu(v.x); r.y = f2bu(v.y); r.z = f2bu(v.z); r.w = f2bu(v.w);
  *(ushort4*)(o + i) = r;
}

// ---------------- 2. transpose-convert weights: W (K x N) f32 -> Wt (N x K) bf16 ----------------
__global__ __launch_bounds__(256) void wtrans_kernel(
    const float* __restrict__ s0, const float* __restrict__ s1, const float* __restrict__ s2,
    const float* __restrict__ s3, const float* __restrict__ s4,
    unsigned short* __restrict__ d0, unsigned short* __restrict__ d1, unsigned short* __restrict__ d2,
    unsigned short* __restrict__ d3, unsigned short* __restrict__ d4) {
  __shared__ float tile[64][65];
  int z = blockIdx.z;
  const float* src = z == 0 ? s0 : z == 1 ? s1 : z == 2 ? s2 : z == 3 ? s3 : s4;
  unsigned short* dst = z == 0 ? d0 : z == 1 ? d1 : z == 2 ? d2 : z == 3 ? d3 : d4;
  int tid = threadIdx.x;
  int by = blockIdx.y * 64;
  int bx = blockIdx.x * 64;
  int r0 = tid >> 4;
  int c0 = (tid & 15) * 4;
#pragma unroll
  for (int i = 0; i < 4; i++) {
    int row = r0 + i * 16;
    float4 t = *(const float4*)(src + (size_t)(by + row) * DM + bx + c0);
    tile[row][c0 + 0] = t.x; tile[row][c0 + 1] = t.y;
    tile[row][c0 + 2] = t.z; tile[row][c0 + 3] = t.w;
  }
  __syncthreads();
#pragma unroll
  for (int i = 0; i < 4; i++) {
    int nrow = r0 + i * 16;
    ushort4 o;
    o.x = f2bu(tile[c0 + 0][nrow]);
    o.y = f2bu(tile[c0 + 1][nrow]);
    o.z = f2bu(tile[c0 + 2][nrow]);
    o.w = f2bu(tile[c0 + 3][nrow]);
    *(ushort4*)(dst + (size_t)(bx + nrow) * DM + by + c0) = o;
  }
}

// ---------------- 3. fused QKVG GEMM (round-4 schedule/mapping, measured 80us) ----------------
// 256x256 tile, 8-wave, 4-phase/K-tile counted-vmcnt. Stage order per tile t+1
// (during tile t): B0@ph0, B1@ph1, A0@ph2, A1@ph3; waits vmcnt(4)@end-ph1,
// vmcnt(2)@end-ph3. XCD mapping: xcd owns one bm-panel (1MB A L2-hot), streams B.
// v-chunk (ch==2) is written TRANSPOSED into vt (fuses away vtrans kernel).
__device__ __forceinline__ void stage_half(const unsigned short* gbase, char* ldsbase, int tid) {
#pragma unroll
  for (int r = 0; r < 2; r++) {
    int a = r * 8192 + tid * 16;
    int row = a >> 7;
    int cb = (a & 127) ^ ((row & 7) << 4);
    async_copy16((const unsigned char*)(gbase + (size_t)row * DM) + cb, ldsbase + a);
  }
}

__global__ __launch_bounds__(512, 2) void gemm_qkvg_kernel(
    const unsigned short* __restrict__ A, const unsigned short* __restrict__ Bm,
    const float* __restrict__ bias0, const float* __restrict__ bias1,
    const float* __restrict__ bias2, const float* __restrict__ bias3,
    unsigned short* __restrict__ C0, unsigned short* __restrict__ C1,
    unsigned short* __restrict__ Vt, unsigned short* __restrict__ C3) {
  __shared__ alignas(16) char smem[131072];
  char* sA = smem;
  char* sB = smem + 65536;
  int tid = threadIdx.x;
  int wg = blockIdx.y * 32 + blockIdx.x;
  int swz = (wg & 7) * 32 + (wg >> 3);
  int bm = (swz >> 5) * 256;
  int bn = (swz & 31) * 256;
  int wid = tid >> 6, lane = tid & 63;
  int wm = wid >> 2, wn = wid & 3;
  int r16 = lane & 15, quad = lane >> 4;
  f32x4 acc[8][4] = {};
  bf16x8 bfrag[2][4];
  const int bhalf = (wn >> 1) << 14;
  const int blr0 = ((wn & 1) << 6) + r16;

  stage_half(Bm + (size_t)bn * DM, sB, tid);
  stage_half(Bm + (size_t)(bn + 128) * DM, sB + 16384, tid);
  stage_half(A + (size_t)bm * DM, sA, tid);
  stage_half(A + (size_t)(bm + 128) * DM, sA + 16384, tid);
  asm volatile("s_waitcnt vmcnt(0)" ::: "memory");
  __builtin_amdgcn_s_barrier();

  for (int t = 0; t < 32; ++t) {
    const int buf = (t & 1) << 15;
    const int nbuf = buf ^ 32768;
    const bool more = t < 31;
    const int kn = (t + 1) * 64;
    char* sAc = sA + buf;
    char* sBc = sB + buf;
    bf16x8 afrag[4];

    // ---- phase 0: read B(kk0)+A0(kk0); stage (t+1).B0
#pragma unroll
    for (int nt = 0; nt < 4; ++nt) {
      int lr = blr0 + nt * 16;
      bfrag[0][nt] = *(const bf16x8*)(sBc + bhalf + lr * 128 + ((quad * 16) ^ ((lr & 7) << 4)));
    }
#pragma unroll
    for (int mt = 0; mt < 4; ++mt) {
      int lr = mt * 32 + wm * 16 + r16;
      afrag[mt] = *(const bf16x8*)(sAc + lr * 128 + ((quad * 16) ^ ((lr & 7) << 4)));
    }
    if (more) stage_half(Bm + (size_t)bn * DM + kn, sB + nbuf, tid);
    __builtin_amdgcn_s_barrier();
    asm volatile("s_waitcnt lgkmcnt(0)" ::: "memory");
    __builtin_amdgcn_s_setprio(1);
#pragma unroll
    for (int mt = 0; mt < 4; ++mt)
#pragma unroll
      for (int nt = 0; nt < 4; ++nt)
        acc[mt][nt] = __builtin_amdgcn_mfma_f32_16x16x32_bf16(afrag[mt], bfrag[0][nt], acc[mt][nt], 0, 0, 0);
    __builtin_amdgcn_s_setprio(0);
    __builtin_amdgcn_s_barrier();

    // ---- phase 1: read B(kk1)+A0(kk1); stage (t+1).B1; close vmcnt(4)
#pragma unroll
    for (int nt = 0; nt < 4; ++nt) {
      int lr = blr0 + nt * 16;
      bfrag[1][nt] = *(const bf16x8*)(sBc + bhalf + lr * 128 + ((64 + quad * 16) ^ ((lr & 7) << 4)));
    }
#pragma unroll
    for (int mt = 0; mt < 4; ++mt) {
      int lr = mt * 32 + wm * 16 + r16;
      afrag[mt] = *(const bf16x8*)(sAc + lr * 128 + ((64 + quad * 16) ^ ((lr & 7) << 4)));
    }
    if (more) stage_half(Bm + (size_t)(bn + 128) * DM + kn, sB + nbuf + 16384, tid);
    __builtin_amdgcn_s_barrier();
    asm volatile("s_waitcnt lgkmcnt(0)" ::: "memory");
    __builtin_amdgcn_s_setprio(1);
#pragma unroll
    for (int mt = 0; mt < 4; ++mt)
#pragma unroll
      for (int nt = 0; nt < 4; ++nt)
        acc[mt][nt] = __builtin_amdgcn_mfma_f32_16x16x32_bf16(afrag[mt], bfrag[1][nt], acc[mt][nt], 0, 0, 0);
    __builtin_amdgcn_s_setprio(0);
    if (more) { asm volatile("s_waitcnt vmcnt(4)" ::: "memory"); }
    else      { asm volatile("s_waitcnt vmcnt(0)" ::: "memory"); }
    __builtin_amdgcn_s_barrier();

    // ---- phase 2: read A1(kk0); stage (t+1).A0; mfma acc[4..7] with held B(kk0)
#pragma unroll
    for (int mt = 0; mt < 4; ++mt) {
      int lr = mt * 32 + wm * 16 + r16;
      afrag[mt] = *(const bf16x8*)(sAc + 16384 + lr * 128 + ((quad * 16) ^ ((lr & 7) << 4)));
    }
    if (more) stage_half(A + (size_t)bm * DM + kn, sA + nbuf, tid);
    __builtin_amdgcn_s_barrier();
    asm volatile("s_waitcnt lgkmcnt(0)" ::: "memory");
    __builtin_amdgcn_s_setprio(1);
#pragma unroll
    for (int mt = 0; mt < 4; ++mt)
#pragma unroll
      for (int nt = 0; nt < 4; ++nt)
        acc[4 + mt][nt] = __builtin_amdgcn_mfma_f32_16x16x32_bf16(afrag[mt], bfrag[0][nt], acc[4 + mt][nt], 0, 0, 0);
    __builtin_amdgcn_s_setprio(0);
    __builtin_amdgcn_s_barrier();

    // ---- phase 3: read A1(kk1); stage (t+1).A1; close vmcnt(2)
#pragma unroll
    for (int mt = 0; mt < 4; ++mt) {
      int lr = mt * 32 + wm * 16 + r16;
      afrag[mt] = *(const bf16x8*)(sAc + 16384 + lr * 128 + ((64 + quad * 16) ^ ((lr & 7) << 4)));
    }
    if (more) stage_half(A + (size_t)(bm + 128) * DM + kn, sA + nbuf + 16384, tid);
    __builtin_amdgcn_s_barrier();
    asm volatile("s_waitcnt lgkmcnt(0)" ::: "memory");
    __builtin_amdgcn_s_setprio(1);
#pragma unroll
    for (int mt = 0; mt < 4; ++mt)
#pragma unroll
      for (int nt = 0; nt < 4; ++nt)
        acc[4 + mt][nt] = __builtin_amdgcn_mfma_f32_16x16x32_bf16(afrag[mt], bfrag[1][nt], acc[4 + mt][nt], 0, 0, 0);
    __builtin_amdgcn_s_setprio(0);
    if (more) { asm volatile("s_waitcnt vmcnt(2)" ::: "memory"); }
    __builtin_amdgcn_s_barrier();
  }

  // epilogue: bn is 256-aligned -> single 2048-wide chunk per block
  int ch = bn >> 11;
  const float* bp = ch == 0 ? bias0 : ch == 1 ? bias1 : ch == 2 ? bias2 : bias3;
  int lcb = bn & 2047;
  if (ch == 2) {
    // v-chunk: write transposed into Vt[feature][seq] (feeds retention directly)
#pragma unroll
    for (int nt = 0; nt < 4; ++nt) {
      int lc = lcb + wn * 64 + nt * 16 + r16;
      float bv = bp[lc];
#pragma unroll
      for (int mt = 0; mt < 8; ++mt) {
        int m0 = bm + (mt >> 2) * 128 + (mt & 3) * 32 + wm * 16 + quad * 4;
        ushort4 o;
        o.x = f2bu(acc[mt][nt][0] + bv);
        o.y = f2bu(acc[mt][nt][1] + bv);
        o.z = f2bu(acc[mt][nt][2] + bv);
        o.w = f2bu(acc[mt][nt][3] + bv);
        *(ushort4*)(Vt + (size_t)lc * DM + m0) = o;
      }
    }
  } else {
    unsigned short* Cp = ch == 0 ? C0 : ch == 1 ? C1 : C3;
#pragma unroll
    for (int nt = 0; nt < 4; ++nt) {
      int lc = lcb + wn * 64 + nt * 16 + r16;
      float bv = bp[lc];
#pragma unroll
      for (int mt = 0; mt < 8; ++mt) {
        int m0 = bm + (mt >> 2) * 128 + (mt & 3) * 32 + wm * 16 + quad * 4;
#pragma unroll
        for (int rr = 0; rr < 4; ++rr)
          Cp[(size_t)(m0 + rr) * DM + lc] = f2bu(acc[mt][nt][rr] + bv);
      }
    }
  }
}

// ---------------- 8. output NT GEMM (128x128 tile) ----------------
__global__ __launch_bounds__(256) void gemm_out_kernel(
    const unsigned short* __restrict__ A, const unsigned short* __restrict__ Bp,
    const float* __restrict__ bias, float* __restrict__ C) {
  __shared__ alignas(16) unsigned char sA[16384];
  __shared__ alignas(16) unsigned char sB[16384];
  int tid = threadIdx.x;
  int bm = blockIdx.y * 128, bn = blockIdx.x * 128;
  int wid = tid >> 6, lane = tid & 63;
  int wm = wid >> 1, wn = wid & 1;
  int r16 = lane & 15, quad = lane >> 4;
  f32x4 acc[4][4] = {};
  for (int kt = 0; kt < DM; kt += 64) {
#pragma unroll
    for (int r = 0; r < 4; r++) {
      int a = r * 4096 + tid * 16;
      int row = a >> 7;
      int cb = (a & 127) ^ ((row & 7) << 4);
      async_copy16((const unsigned char*)(A + (size_t)(bm + row) * DM + kt) + cb, sA + a);
      async_copy16((const unsigned char*)(Bp + (size_t)(bn + row) * DM + kt) + cb, sB + a);
    }
    __syncthreads();
#pragma unroll
    for (int kk = 0; kk < 2; kk++) {
      bf16x8 af[4], bfr[4];
#pragma unroll
      for (int mt = 0; mt < 4; mt++) {
        int row = wm * 64 + mt * 16 + r16;
        af[mt] = *(const bf16x8*)(sA + row * 128 + ((quad * 16 + kk * 64) ^ ((row & 7) << 4)));
      }
#pragma unroll
      for (int nt = 0; nt < 4; nt++) {
        int row = wn * 64 + nt * 16 + r16;
        bfr[nt] = *(const bf16x8*)(sB + row * 128 + ((quad * 16 + kk * 64) ^ ((row & 7) << 4)));
      }
#pragma unroll
      for (int mt = 0; mt < 4; mt++)
#pragma unroll
        for (int nt = 0; nt < 4; nt++)
          acc[mt][nt] = __builtin_amdgcn_mfma_f32_16x16x32_bf16(af[mt], bfr[nt], acc[mt][nt], 0, 0, 0);
    }
    __syncthreads();
  }
#pragma unroll
  for (int nt = 0; nt < 4; nt++) {
    int n = bn + wn * 64 + nt * 16 + r16;
    float bv = bias[n];
#pragma unroll
    for (int mt = 0; mt < 4; mt++) {
      int m0 = bm + wm * 64 + mt * 16 + quad * 4;
#pragma unroll
      for (int r = 0; r < 4; r++)
        C[(size_t)(m0 + r) * DM + n] = acc[mt][nt][r] + bv;
    }
  }
}

// ---------------- 4. RoPE + xPos + decay pre-fold (in-place on q,k bf16) ----------------
__global__ __launch_bounds__(256) void rope_kernel(unsigned short* __restrict__ q,
                                                   unsigned short* __restrict__ k) {
  int idx = blockIdx.x * 256 + threadIdx.x;
  int s = idx >> 10;
  int p = idx & 1023;
  int t = p & 63;
  int head = p >> 6;
  int col = (head << 7) + (t << 1);
  size_t off = (size_t)s * DM + col;
  float ang = (float)s * exp2f((float)(-2 * t) * (13.287712379549449f / 128.0f));
  float sn, cs;
  sincosf(ang, &sn, &cs);
  float sb = ((float)(2 * t) + 51.2f) * (1.0f / 179.2f);
  float power = ((float)s - 1024.0f) * (1.0f / 512.0f);
  float scale = exp2f(power * log2f(sb));
  float l2g = log2f(1.0f - exp2f((float)(-5 - head)));
  float qsc = scale * exp2f((float)s * l2g);
  float ksc = (1.0f / scale) * exp2f(-(float)s * l2g);
  unsigned int qu = *(unsigned int*)(q + off);
  float a = bu2f(qu & 0xffff), b = bu2f(qu >> 16);
  float qa = (a * cs - b * sn) * qsc;
  float qb2 = (b * cs + a * sn) * qsc;
  *(unsigned int*)(q + off) = (unsigned int)f2bu(qa) | ((unsigned int)f2bu(qb2) << 16);
  unsigned int ku = *(unsigned int*)(k + off);
  float c2 = bu2f(ku & 0xffff), d2 = bu2f(ku >> 16);
  float ka = (c2 * cs - d2 * sn) * ksc;
  float kb2 = (d2 * cs + c2 * sn) * ksc;
  *(unsigned int*)(k + off) = (unsigned int)f2bu(ka) | ((unsigned int)f2bu(kb2) << 16);
}

// ---------------- 6. retention + fused GroupNorm/SiLU gate -> y (bf16) ----------------
__device__ __forceinline__ void stage_kv(const unsigned short* __restrict__ k,
                                         const unsigned short* __restrict__ vt,
                                         int h, int J0, unsigned char* dK,
                                         unsigned char* dV, int tid) {
#pragma unroll
  for (int r = 0; r < 4; r++) {
    int a = r * 4096 + tid * 16;
    int rowk = a >> 8;
    int cbk = (a & 255) ^ ((rowk & 7) << 4);
    async_copy16((const unsigned char*)(k + (size_t)(J0 + rowk) * DM + h * HD) + cbk, dK + a);
    int rowv = a >> 7;
    int cbv = (a & 127) ^ ((rowv & 7) << 4);
    async_copy16((const unsigned char*)(vt + (size_t)(h * HD + rowv) * DM + J0) + cbv, dV + a);
  }
}

__global__ __launch_bounds__(256) void retention_kernel(
    const unsigned short* __restrict__ q, const unsigned short* __restrict__ k,
    const unsigned short* __restrict__ vt, const unsigned short* __restrict__ g,
    unsigned short* __restrict__ y) {
  __shared__ alignas(16) unsigned char sK[2][16384];
  __shared__ alignas(16) unsigned char sV[2][16384];
  __shared__ alignas(16) unsigned char Plds[8192];
  int bx = blockIdx.x;
  int hi = bx >> 8;
  int h = ((bx >> 5) & 7) | (hi << 3);
  int ib = hi ? (bx & 31) : (31 - (bx & 31));
  int I = ib << 6;
  int tid = threadIdx.x, wid = tid >> 6, lane = tid & 63;
  int r16 = lane & 15, quad = lane >> 4;
  bf16x8 aQ[4];
  size_t qrow = (size_t)(I + wid * 16 + r16);
#pragma unroll
  for (int kk = 0; kk < 4; kk++)
    aQ[kk] = *(const bf16x8*)(q + qrow * DM + h * HD + kk * 32 + quad * 8);
  f32x4 acc[8] = {};
  unsigned char* Pw = Plds + wid * 2048;
  stage_kv(k, vt, h, 0, sK[0], sV[0], tid);
  for (int J0 = 0; J0 <= I; J0 += 64) {
    int cur = (J0 >> 6) & 1;
    bool more = (J0 + 64) <= I;
    if (more) stage_kv(k, vt, h, J0 + 64, sK[cur ^ 1], sV[cur ^ 1], tid);
    if (more) { asm volatile("s_waitcnt vmcnt(8)" ::: "memory"); }
    else      { asm volatile("s_waitcnt vmcnt(0)" ::: "memory"); }
    __builtin_amdgcn_s_barrier();
    const unsigned char* sKc = sK[cur];
    const unsigned char* sVc = sV[cur];
    // QK^T
    f32x4 sf[4] = {};
#pragma unroll
    for (int nt = 0; nt < 4; nt++) {
      int row = nt * 16 + r16;
#pragma unroll
      for (int kk = 0; kk < 4; kk++) {
        bf16x8 bK = *(const bf16x8*)(sKc + row * 256 + ((kk * 64 + quad * 16) ^ ((row & 7) << 4)));
        sf[nt] = __builtin_amdgcn_mfma_f32_16x16x32_bf16(aQ[kk], bK, sf[nt], 0, 0, 0);
      }
    }
    bool diag = (J0 == I);
#pragma unroll
    for (int nt = 0; nt < 4; nt++) {
      int j = nt * 16 + r16;
#pragma unroll
      for (int r = 0; r < 4; r++) {
        int ii = wid * 16 + quad * 4 + r;
        float pv = sf[nt][r];
        if (diag && (ii - j) < 0) pv = 0.0f;
        int pr = quad * 4 + r;
        int pcb = (nt * 16 + r16) * 2;
        *(unsigned short*)(Pw + pr * 128 + (pcb ^ ((pr & 7) << 4))) = f2bu(pv);
      }
    }
    // P @ V
#pragma unroll
    for (int kk2 = 0; kk2 < 2; kk2++) {
      int cb = kk2 * 64 + quad * 16;
      bf16x8 aP = *(const bf16x8*)(Pw + r16 * 128 + (cb ^ ((r16 & 7) << 4)));
#pragma unroll
      for (int nt2 = 0; nt2 < 8; nt2++) {
        int row = nt2 * 16 + r16;
        bf16x8 bV = *(const bf16x8*)(sVc + row * 128 + ((kk2 * 64 + quad * 16) ^ ((row & 7) << 4)));
        acc[nt2] = __builtin_amdgcn_mfma_f32_16x16x32_bf16(aP, bV, acc[nt2], 0, 0, 0);
      }
    }
    __builtin_amdgcn_s_barrier();
  }
  // fused GroupNorm (per row over 128) + SiLU(g) gate -> y bf16.
  // Row (quad,r) lives across the 16 lanes sharing quad; each lane holds cols
  // {r16, 16+r16, ..., 112+r16}. shfl_xor widths 1..8 reduce within the quad group.
#pragma unroll
  for (int r = 0; r < 4; r++) {
    float sum = 0.0f, sq = 0.0f;
#pragma unroll
    for (int nt2 = 0; nt2 < 8; nt2++) {
      float v = acc[nt2][r];
      sum += v; sq += v * v;
    }
#pragma unroll
    for (int o = 1; o <= 8; o <<= 1) {
      sum += __shfl_xor(sum, o, 64);
      sq += __shfl_xor(sq, o, 64);
    }
    float mean = sum * 0.0078125f;
    float var = sq * 0.0078125f - mean * mean;
    float rstd = rsqrtf(var + 1e-5f);
    int i = I + wid * 16 + quad * 4 + r;
    size_t rowbase = (size_t)i * DM + h * HD;
#pragma unroll
    for (int nt2 = 0; nt2 < 8; nt2++) {
      int col = nt2 * 16 + r16;
      float gv = bu2f(g[rowbase + col]);
      float sg = gv / (1.0f + expf(-gv));
      float yv = sg * (acc[nt2][r] - mean) * rstd;
      y[rowbase + col] = f2bu(yv);
    }
  }
}

extern "C" void kernel_launch(void* const* d_in, const int* in_sizes, int n_in,
                              void* d_out, int out_size, void* d_ws, size_t ws_size,
                              hipStream_t stream) {
  (void)in_sizes; (void)n_in; (void)out_size; (void)ws_size;
  const float* x  = (const float*)d_in[0];
  const float* Wq = (const float*)d_in[1];
  const float* bq = (const float*)d_in[2];
  const float* Wk = (const float*)d_in[3];
  const float* bk = (const float*)d_in[4];
  const float* Wv = (const float*)d_in[5];
  const float* bv = (const float*)d_in[6];
  const float* Wg = (const float*)d_in[7];
  const float* bg = (const float*)d_in[8];
  const float* Wo = (const float*)d_in[9];
  const float* bo = (const float*)d_in[10];

  char* ws = (char*)d_ws;
  const size_t MB = 1ull << 20;
  unsigned short* xb   = (unsigned short*)(ws + 0 * MB);
  unsigned short* wcat = (unsigned short*)(ws + 8 * MB);   // 8192 x 2048 bf16 (q|k|v|g)
  unsigned short* wto  = (unsigned short*)(ws + 40 * MB);
  unsigned short* qb   = (unsigned short*)(ws + 48 * MB);
  unsigned short* kb   = (unsigned short*)(ws + 56 * MB);
  unsigned short* gb   = (unsigned short*)(ws + 72 * MB);
  unsigned short* vt   = (unsigned short*)(ws + 80 * MB);
  unsigned short* yb   = (unsigned short*)(ws + 104 * MB);

  cvt_kernel<<<4096, 256, 0, stream>>>(x, xb);
  wtrans_kernel<<<dim3(32, 32, 5), 256, 0, stream>>>(
      Wq, Wk, Wv, Wg, Wo,
      wcat, wcat + (size_t)2048 * DM, wcat + (size_t)4096 * DM, wcat + (size_t)6144 * DM, wto);
  gemm_qkvg_kernel<<<dim3(32, 8), 512, 0, stream>>>(
      xb, wcat, bq, bk, bv, bg, qb, kb, vt, gb);
  rope_kernel<<<8192, 256, 0, stream>>>(qb, kb);
  retention_kernel<<<512, 256, 0, stream>>>(qb, kb, vt, gb, yb);
  gemm_out_kernel<<<dim3(16, 16), 256, 0, stream>>>(yb, wto, bo, (float*)d_out);
}